// Round 2
// baseline (493.879 us; speedup 1.0000x reference)
//
#include <hip/hip_runtime.h>
#include <stdint.h>

typedef _Float16 f16;
typedef _Float16 half8 __attribute__((ext_vector_type(8)));
typedef float f32x4 __attribute__((ext_vector_type(4)));

#define NBATCH 16
#define NTOK 3136
#define NH 8
#define NA 49
#define NAP 64
#define TTOP 1568
#define QLD 768
#define SCALE 0.17677669529663687f

__device__ __forceinline__ f32x4 mfma16(half8 a, half8 b, f32x4 c) {
  return __builtin_amdgcn_mfma_f32_16x16x32_f16(a, b, c, 0, 0, 0);
}

// ---------------- weight conversion ----------------
__global__ __launch_bounds__(256) void k_prep_w(const float* Wq, const float* Wkv, const float* Wproj,
                                                f16* wqkv, f16* wproj) {
  int total1 = 768 * 256;
  int total = total1 + 256 * 256;
  for (int i = blockIdx.x * 256 + threadIdx.x; i < total; i += gridDim.x * 256) {
    if (i < total1) {
      int j = i >> 8, k = i & 255;
      float v = (j < 256) ? Wq[j * 256 + k] : Wkv[(j - 256) * 256 + k];
      wqkv[i] = (f16)v;
    } else {
      int i2 = i - total1;
      wproj[i2] = (f16)Wproj[i2];
    }
  }
}

// ---------------- x f32 -> f16 ----------------
__global__ __launch_bounds__(256) void k_cvt_x(const float* x, f16* xh, long total) {
  long i = (long)blockIdx.x * blockDim.x + threadIdx.x;
  long stride = (long)gridDim.x * blockDim.x;
  for (long e = i * 8; e < total; e += stride * 8) {
    float4 v0 = *(const float4*)(x + e);
    float4 v1 = *(const float4*)(x + e + 4);
    half8 o = {(f16)v0.x, (f16)v0.y, (f16)v0.z, (f16)v0.w,
               (f16)v1.x, (f16)v1.y, (f16)v1.z, (f16)v1.w};
    *(half8*)(xh + e) = o;
  }
}

// ---------------- bias precompute ----------------
// pos_bias[h][a(64)][n]  = up(an_bias)[h,a,y,x] + ah[h,a,y] + aw[h,a,x]
// agent_bias[h][n][a(64)] = up(na_bias)[h,a,y,x] + ha[h,y,a] + wa[h,x,a]
__global__ __launch_bounds__(256) void k_bias(const float* an_b, const float* na_b,
                                              const float* ah_b, const float* aw_b,
                                              const float* ha_b, const float* wa_b,
                                              float* pos_bias, float* agent_bias) {
  int n = blockIdx.x * 256 + threadIdx.x;
  int h = blockIdx.y;
  if (n >= NTOK) return;
  int y = n / 56, x = n - y * 56;
  float py = (y + 0.5f) * 0.125f - 0.5f;
  float px = (x + 0.5f) * 0.125f - 0.5f;
  int iy0 = (int)floorf(py); float fy = py - (float)iy0;
  int ix0 = (int)floorf(px); float fx = px - (float)ix0;
  int y0 = max(iy0, 0), y1 = min(iy0 + 1, 6);
  int x0 = max(ix0, 0), x1 = min(ix0 + 1, 6);
  float w00 = (1.f - fy) * (1.f - fx), w01 = (1.f - fy) * fx;
  float w10 = fy * (1.f - fx), w11 = fy * fx;
  for (int a = 0; a < NA; ++a) {
    const float* pa = an_b + (h * NA + a) * 49;
    float up_an = w00 * pa[y0 * 7 + x0] + w01 * pa[y0 * 7 + x1] +
                  w10 * pa[y1 * 7 + x0] + w11 * pa[y1 * 7 + x1];
    const float* pn = na_b + (h * NA + a) * 49;
    float up_na = w00 * pn[y0 * 7 + x0] + w01 * pn[y0 * 7 + x1] +
                  w10 * pn[y1 * 7 + x0] + w11 * pn[y1 * 7 + x1];
    float pb = up_an + ah_b[(h * NA + a) * 56 + y] + aw_b[(h * NA + a) * 56 + x];
    pos_bias[((size_t)(h * NAP + a)) * NTOK + n] = pb;
    float ab = up_na + ha_b[(h * 56 + y) * NA + a] + wa_b[(h * 56 + x) * NA + a];
    agent_bias[((size_t)(h * NTOK + n)) * NAP + a] = ab;
  }
  for (int a = NA; a < NAP; ++a) {
    pos_bias[((size_t)(h * NAP + a)) * NTOK + n] = 0.f;
    agent_bias[((size_t)(h * NTOK + n)) * NAP + a] = 0.f;
  }
}

// ---------------- generic f16 MFMA GEMM: C[M,N] = A[M,256] * Bw[N,256]^T ----------------
// BM=BN=128, BK=32, 256 threads (4 waves, 2x2 of 64x64)
// LDS: row stride 80 bytes (64B data + 16B pad) -> max 2-way bank conflict, no swizzle.
template <bool PROJ>
__global__ __launch_bounds__(256) void k_gemm(const f16* __restrict__ A, const f16* __restrict__ Bw,
                                              f16* __restrict__ Cf16, float* __restrict__ Cf32,
                                              const float* __restrict__ bias, int N) {
  __shared__ __align__(16) char lds[2 * 128 * 80];
  int n0 = blockIdx.x * 128;
  int m0 = blockIdx.y * 128;
  int tid = threadIdx.x, w = tid >> 6, l = tid & 63, lr = l & 15, lg = l >> 4;
  int wm = w >> 1, wn = w & 1;
  f32x4 acc[4][4] = {};
  const char* Abase = (const char*)A + (size_t)m0 * 512;
  const char* Bbase = (const char*)Bw + (size_t)n0 * 512;
  for (int k0 = 0; k0 < 256; k0 += 32) {
#pragma unroll
    for (int rd = 0; rd < 2; ++rd) {
      int chunk = rd * 256 + tid;     // 512 chunks of 16B cover 128 rows x 64B
      int r = chunk >> 2;             // row 0..127
      int koff = (chunk & 3) * 16;    // byte offset within row's 64B
      half8 va = *(const half8*)(Abase + (size_t)r * 512 + k0 * 2 + koff);
      half8 vb = *(const half8*)(Bbase + (size_t)r * 512 + k0 * 2 + koff);
      *(half8*)(lds + r * 80 + koff) = va;
      *(half8*)(lds + 10240 + r * 80 + koff) = vb;
    }
    __syncthreads();
    half8 af[4], bf[4];
#pragma unroll
    for (int mt = 0; mt < 4; ++mt) {
      int row = wm * 64 + mt * 16 + lr;
      af[mt] = *(const half8*)(lds + row * 80 + lg * 16);
    }
#pragma unroll
    for (int nt = 0; nt < 4; ++nt) {
      int row = wn * 64 + nt * 16 + lr;
      bf[nt] = *(const half8*)(lds + 10240 + row * 80 + lg * 16);
    }
#pragma unroll
    for (int mt = 0; mt < 4; ++mt)
#pragma unroll
      for (int nt = 0; nt < 4; ++nt)
        acc[mt][nt] = mfma16(af[mt], bf[nt], acc[mt][nt]);
    __syncthreads();
  }
#pragma unroll
  for (int mt = 0; mt < 4; ++mt)
#pragma unroll
    for (int nt = 0; nt < 4; ++nt)
#pragma unroll
      for (int r = 0; r < 4; ++r) {
        int m = m0 + wm * 64 + mt * 16 + lg * 4 + r;
        int n = n0 + wn * 64 + nt * 16 + lr;
        if (PROJ)
          Cf32[(size_t)m * N + n] = acc[mt][nt][r] + bias[n];
        else
          Cf16[(size_t)m * N + n] = (f16)acc[mt][nt][r];
      }
}

// ---------------- agent pooling (scaled) + token means ----------------
__global__ __launch_bounds__(256) void k_pool_tw(const f16* qkv, f16* agent, float* tw) {
  int bh = blockIdx.x, b = bh >> 3, h = bh & 7;
  int tid = threadIdx.x;
  for (int s = tid; s < NAP * 32; s += 256) {
    int a = s >> 5, d = s & 31;
    float val = 0.f;
    if (a < NA) {
      int dh = a / 7, dwi = a - dh * 7;
      float sum = 0.f;
      for (int i = 0; i < 8; ++i)
        for (int j = 0; j < 8; ++j) {
          int n = (dh * 8 + i) * 56 + dwi * 8 + j;
          sum += (float)qkv[((size_t)(b * NTOK + n)) * QLD + h * 32 + d];
        }
      val = sum * (SCALE / 64.f);
    }
    agent[(size_t)bh * NAP * 32 + s] = (f16)val;
  }
  for (int n = tid; n < NTOK; n += 256) {
    const f16* qp = qkv + ((size_t)(b * NTOK + n)) * QLD + h * 32;
    float sum = 0.f;
    for (int d = 0; d < 32; ++d) sum += (float)qp[d];
    tw[(size_t)bh * NTOK + n] = sum * (1.f / 32.f);
  }
}

// ---------------- exact top-k (desc value, asc index) via bitonic sort ----------------
__global__ __launch_bounds__(256) void k_topk(const float* tw, int* topidx) {
  __shared__ unsigned long long keys[4096];
  int bh = blockIdx.x, tid = threadIdx.x;
  const float* p = tw + (size_t)bh * NTOK;
  for (int s = tid; s < 4096; s += 256) {
    float v = (s < NTOK) ? p[s] : -1e30f;
    unsigned ub = __float_as_uint(v);
    ub = (ub & 0x80000000u) ? ~ub : (ub | 0x80000000u);
    unsigned low = (s < NTOK) ? ~(unsigned)s : 0u;
    keys[s] = ((unsigned long long)ub << 32) | low;
  }
  for (int k = 2; k <= 4096; k <<= 1)
    for (int j = k >> 1; j > 0; j >>= 1) {
      __syncthreads();
      for (int i = tid; i < 4096; i += 256) {
        int ixj = i ^ j;
        if (ixj > i) {
          unsigned long long a = keys[i], c = keys[ixj];
          bool lt = a < c;
          bool descRegion = ((i & k) == 0);
          if (lt == descRegion) { keys[i] = c; keys[ixj] = a; }
        }
      }
    }
  __syncthreads();
  for (int t = tid; t < TTOP; t += 256)
    topidx[(size_t)bh * TTOP + t] = (int)(~(unsigned)keys[t]);
}

// ---------------- v transpose: vt[bh][d=32][n=3136] ----------------
__global__ __launch_bounds__(256) void k_vt(const f16* qkv, f16* vt) {
  __shared__ f16 t[64][33];
  int bh = blockIdx.y, b = bh >> 3, h = bh & 7;
  int n0 = blockIdx.x * 64;
  int tid = threadIdx.x;
  for (int s = tid; s < 64 * 32; s += 256) {
    int nl = s >> 5, d = s & 31;
    t[nl][d] = qkv[((size_t)(b * NTOK + n0 + nl)) * QLD + 512 + h * 32 + d];
  }
  __syncthreads();
  for (int s = tid; s < 64 * 32; s += 256) {
    int d = s >> 6, nl = s & 63;
    vt[((size_t)(bh * 32 + d)) * NTOK + n0 + nl] = t[nl][d];
  }
}

// ---------------- fused agent attention: softmax_n(agent_s . k^T + bias) @ v ----------------
__global__ __launch_bounds__(256) void k_flash(const f16* qkv, const f16* agent, const f16* vt,
                                               const float* pos_bias, float* agent_v) {
  __shared__ __align__(16) f16 pbuf[4][64][40];
  __shared__ float ored[64][33];
  __shared__ float rssum[64];
  int bh = blockIdx.x, b = bh >> 3, h = bh & 7;
  int tid = threadIdx.x, w = tid >> 6, l = tid & 63, lr = l & 15, lg = l >> 4;
  half8 afrag[4];
#pragma unroll
  for (int mt = 0; mt < 4; ++mt)
    afrag[mt] = *(const half8*)(agent + ((size_t)bh * 64 + mt * 16 + lr) * 32 + lg * 8);
  f32x4 o[4][2] = {};
  float rs[4][4] = {};
  const f16* kbase = qkv + (size_t)b * NTOK * QLD + 256 + h * 32;
  const f16* vtb = vt + (size_t)bh * 32 * NTOK;
  const float* pbb = pos_bias + (size_t)h * NAP * NTOK;
  f32x4 zero = {};
  for (int n0 = w * 32; n0 < NTOK; n0 += 128) {
#pragma unroll
    for (int t2 = 0; t2 < 2; ++t2) {
      int nc = n0 + t2 * 16;
      half8 kf = *(const half8*)(kbase + (size_t)(nc + lr) * QLD + lg * 8);
#pragma unroll
      for (int mt = 0; mt < 4; ++mt) {
        f32x4 s = mfma16(afrag[mt], kf, zero);
#pragma unroll
        for (int r = 0; r < 4; ++r) {
          int a = mt * 16 + lg * 4 + r;
          float pv = __expf(s[r] + pbb[(size_t)a * NTOK + nc + lr]);
          rs[mt][r] += pv;
          pbuf[w][a][t2 * 16 + lr] = (f16)pv;
        }
      }
    }
    half8 pf[4];
#pragma unroll
    for (int mt = 0; mt < 4; ++mt)
      pf[mt] = *(const half8*)(&pbuf[w][mt * 16 + lr][lg * 8]);
#pragma unroll
    for (int dt = 0; dt < 2; ++dt) {
      half8 vf = *(const half8*)(vtb + (size_t)(dt * 16 + lr) * NTOK + n0 + lg * 8);
#pragma unroll
      for (int mt = 0; mt < 4; ++mt)
        o[mt][dt] = mfma16(pf[mt], vf, o[mt][dt]);
    }
  }
  // reduce row sums within 16-lane groups
#pragma unroll
  for (int mt = 0; mt < 4; ++mt)
#pragma unroll
    for (int r = 0; r < 4; ++r) {
      float v = rs[mt][r];
      for (int off = 1; off < 16; off <<= 1) v += __shfl_xor(v, off, 64);
      rs[mt][r] = v;
    }
  for (int s = tid; s < 64 * 33; s += 256) ((float*)ored)[s] = 0.f;
  if (tid < 64) rssum[tid] = 0.f;
  __syncthreads();
  for (int ww = 0; ww < 4; ++ww) {
    if (w == ww) {
      if (lr == 0)
#pragma unroll
        for (int mt = 0; mt < 4; ++mt)
#pragma unroll
          for (int r = 0; r < 4; ++r) rssum[mt * 16 + lg * 4 + r] += rs[mt][r];
#pragma unroll
      for (int mt = 0; mt < 4; ++mt)
#pragma unroll
        for (int dt = 0; dt < 2; ++dt)
#pragma unroll
          for (int r = 0; r < 4; ++r)
            ored[mt * 16 + lg * 4 + r][dt * 16 + lr] += o[mt][dt][r];
    }
    __syncthreads();
  }
  for (int s = tid; s < NA * 32; s += 256) {
    int a = s >> 5, d = s & 31;
    agent_v[(size_t)bh * NA * 32 + s] = ored[a][d] / rssum[a];
  }
}

// ---------------- fused: q2 (gathered) -> resize -> softmax_a -> @agent_v, + dwconv ----------------
__global__ __launch_bounds__(256) void k_second(const f16* qkv, const f16* agent, const int* topidx,
                                                const float* agent_v, const float* agent_bias,
                                                const float* dwc_w, const float* dwc_b, f16* pre) {
  __shared__ float q2buf[160][68];
  __shared__ float av[NA][32];
  __shared__ float wconv[32][9];
  __shared__ float bconv[32];
  int chunk = blockIdx.x, bh = blockIdx.y, b = bh >> 3, h = bh & 7;
  int tid = threadIdx.x, w = tid >> 6, l = tid & 63, lr = l & 15, lg = l >> 4;
  for (int s = tid; s < NA * 32; s += 256) ((float*)av)[s] = agent_v[(size_t)bh * NA * 32 + s];
  for (int s = tid; s < 32 * 9; s += 256) ((float*)wconv)[s] = dwc_w[(size_t)(h * 32) * 9 + s];
  if (tid < 32) bconv[tid] = dwc_b[h * 32 + tid];
  half8 bfrag[4];
#pragma unroll
  for (int nt = 0; nt < 4; ++nt)
    bfrag[nt] = *(const half8*)(agent + ((size_t)bh * 64 + nt * 16 + lr) * 32 + lg * 8);
  int jbase = chunk * 128 - 16;
  f32x4 zero = {};
  for (int mt = w; mt < 10; mt += 4) {
    int j = jbase + mt * 16 + lr;
    int jc = min(max(j, 0), TTOP - 1);
    int tok = topidx[(size_t)bh * TTOP + jc];
    half8 qf = *(const half8*)(qkv + ((size_t)(b * NTOK + tok)) * QLD + h * 32 + lg * 8);
#pragma unroll
    for (int nt = 0; nt < 4; ++nt) {
      f32x4 s = mfma16(qf, bfrag[nt], zero);
#pragma unroll
      for (int r = 0; r < 4; ++r)
        q2buf[mt * 16 + lg * 4 + r][nt * 16 + lr] = s[r];
    }
  }
  __syncthreads();
  int i = chunk * 256 + tid;
  if (i >= NTOK) return;
  int y = i / 56, x = i - y * 56;
  int hi = i >> 1;
  int jA, jB; float wA, wB;
  if (i & 1) { jA = hi; jB = hi + 1; wA = 0.75f; wB = 0.25f; }
  else       { jA = hi - 1; jB = hi; wA = 0.25f; wB = 0.75f; }
  jA = min(max(jA, 0), TTOP - 1);
  jB = min(max(jB, 0), TTOP - 1);
  int lA = jA - jbase, lB = jB - jbase;
  const float* ab = agent_bias + ((size_t)(h * NTOK + i)) * NAP;
  float mx = -1e30f;
  for (int a = 0; a < NA; ++a) {
    float v = wA * q2buf[lA][a] + wB * q2buf[lB][a] + ab[a];
    mx = fmaxf(mx, v);
  }
  float acc[32] = {};
  float ssum = 0.f;
  for (int a = 0; a < NA; ++a) {
    float v = wA * q2buf[lA][a] + wB * q2buf[lB][a] + ab[a];
    float pv = __expf(v - mx);
    ssum += pv;
#pragma unroll
    for (int d = 0; d < 32; ++d) acc[d] += pv * av[a][d];
  }
  float inv = 1.f / ssum;
  float dwv[32];
#pragma unroll
  for (int d = 0; d < 32; ++d) dwv[d] = bconv[d];
  for (int ky = 0; ky < 3; ++ky) {
    int yy = y + ky - 1;
    if (yy < 0 || yy >= 56) continue;
    for (int kx = 0; kx < 3; ++kx) {
      int xx = x + kx - 1;
      if (xx < 0 || xx >= 56) continue;
      const f16* vp = qkv + ((size_t)(b * NTOK + yy * 56 + xx)) * QLD + 512 + h * 32;
#pragma unroll
      for (int d = 0; d < 32; ++d) dwv[d] += wconv[d][ky * 3 + kx] * (float)vp[d];
    }
  }
  f16* op = pre + ((size_t)(b * NTOK + i)) * 256 + h * 32;
#pragma unroll
  for (int d = 0; d < 32; ++d) op[d] = (f16)(acc[d] * inv + dwv[d]);
}

extern "C" void kernel_launch(void* const* d_in, const int* in_sizes, int n_in,
                              void* d_out, int out_size, void* d_ws, size_t ws_size,
                              hipStream_t stream) {
  const float* x     = (const float*)d_in[0];
  const float* Wq    = (const float*)d_in[3];
  const float* Wkv   = (const float*)d_in[4];
  const float* Wproj = (const float*)d_in[5];
  const float* bproj = (const float*)d_in[6];
  const float* dwc_w = (const float*)d_in[7];
  const float* dwc_b = (const float*)d_in[8];
  const float* an_b  = (const float*)d_in[9];
  const float* na_b  = (const float*)d_in[10];
  const float* ah_b  = (const float*)d_in[11];
  const float* aw_b  = (const float*)d_in[12];
  const float* ha_b  = (const float*)d_in[13];
  const float* wa_b  = (const float*)d_in[14];

  char* ws = (char*)d_ws;
  size_t off = 0;
  auto alloc = [&](size_t bytes) {
    void* p = ws + off;
    off = (off + bytes + 255) & ~(size_t)255;
    return p;
  };
  f16* xh      = (f16*)alloc((size_t)50176 * 256 * 2);
  f16* wqkv    = (f16*)alloc((size_t)768 * 256 * 2);
  f16* wproj   = (f16*)alloc((size_t)256 * 256 * 2);
  f16* qkv     = (f16*)alloc((size_t)50176 * 768 * 2);
  float* posb  = (float*)alloc((size_t)8 * NAP * NTOK * 4);
  float* agb   = (float*)alloc((size_t)8 * NTOK * NAP * 4);
  f16* agent   = (f16*)alloc((size_t)128 * NAP * 32 * 2);
  float* tw    = (float*)alloc((size_t)128 * NTOK * 4);
  int* topidx  = (int*)alloc((size_t)128 * TTOP * 4);
  f16* vt      = (f16*)alloc((size_t)128 * 32 * NTOK * 2);
  float* agv   = (float*)alloc((size_t)128 * NA * 32 * 4);
  f16* pre     = xh;  // reuse: xh dead after qkv GEMM

  k_prep_w<<<1024, 256, 0, stream>>>(Wq, Wkv, Wproj, wqkv, wproj);
  k_cvt_x<<<2048, 256, 0, stream>>>(x, xh, (long)50176 * 256);
  k_bias<<<dim3(13, 8), 256, 0, stream>>>(an_b, na_b, ah_b, aw_b, ha_b, wa_b, posb, agb);
  k_gemm<false><<<dim3(6, 392), 256, 0, stream>>>(xh, wqkv, qkv, nullptr, nullptr, 768);
  k_pool_tw<<<128, 256, 0, stream>>>(qkv, agent, tw);
  k_topk<<<128, 256, 0, stream>>>(tw, topidx);
  k_vt<<<dim3(49, 128), 256, 0, stream>>>(qkv, vt);
  k_flash<<<128, 256, 0, stream>>>(qkv, agent, vt, posb, agv);
  k_second<<<dim3(13, 128), 256, 0, stream>>>(qkv, agent, topidx, agv, agb, dwc_w, dwc_b, pre);
  k_gemm<true><<<dim3(2, 392), 256, 0, stream>>>(pre, wproj, nullptr, (float*)d_out, bproj, 256);
}

// Round 3
// 430.289 us; speedup vs baseline: 1.1478x; 1.1478x over previous
//
#include <hip/hip_runtime.h>
#include <stdint.h>

typedef _Float16 f16;
typedef _Float16 half8 __attribute__((ext_vector_type(8)));
typedef float f32x4 __attribute__((ext_vector_type(4)));

#define NBATCH 16
#define NTOK 3136
#define NH 8
#define NA 49
#define NAP 64
#define TTOP 1568
#define QLD 768
#define SCALE 0.17677669529663687f

__device__ __forceinline__ f32x4 mfma16(half8 a, half8 b, f32x4 c) {
  return __builtin_amdgcn_mfma_f32_16x16x32_f16(a, b, c, 0, 0, 0);
}

// ---------------- weight conversion ----------------
__global__ __launch_bounds__(256) void k_prep_w(const float* Wq, const float* Wkv, const float* Wproj,
                                                f16* wqkv, f16* wproj) {
  int total1 = 768 * 256;
  int total = total1 + 256 * 256;
  for (int i = blockIdx.x * 256 + threadIdx.x; i < total; i += gridDim.x * 256) {
    if (i < total1) {
      int j = i >> 8, k = i & 255;
      float v = (j < 256) ? Wq[j * 256 + k] : Wkv[(j - 256) * 256 + k];
      wqkv[i] = (f16)v;
    } else {
      int i2 = i - total1;
      wproj[i2] = (f16)Wproj[i2];
    }
  }
}

// ---------------- bias precompute ----------------
// pos_bias[h][a(64)][n]   = up(an_bias)[h,a,y,x] + ah[h,a,y] + aw[h,a,x]
// agent_bias[h][a(64)][n] = up(na_bias)[h,a,y,x] + ha[h,y,a] + wa[h,x,a]   (TRANSPOSED: n-major)
__global__ __launch_bounds__(256) void k_bias(const float* an_b, const float* na_b,
                                              const float* ah_b, const float* aw_b,
                                              const float* ha_b, const float* wa_b,
                                              float* pos_bias, float* agent_bias) {
  int n = blockIdx.x * 256 + threadIdx.x;
  int h = blockIdx.y;
  if (n >= NTOK) return;
  int y = n / 56, x = n - y * 56;
  float py = (y + 0.5f) * 0.125f - 0.5f;
  float px = (x + 0.5f) * 0.125f - 0.5f;
  int iy0 = (int)floorf(py); float fy = py - (float)iy0;
  int ix0 = (int)floorf(px); float fx = px - (float)ix0;
  int y0 = max(iy0, 0), y1 = min(iy0 + 1, 6);
  int x0 = max(ix0, 0), x1 = min(ix0 + 1, 6);
  float w00 = (1.f - fy) * (1.f - fx), w01 = (1.f - fy) * fx;
  float w10 = fy * (1.f - fx), w11 = fy * fx;
  for (int a = 0; a < NA; ++a) {
    const float* pa = an_b + (h * NA + a) * 49;
    float up_an = w00 * pa[y0 * 7 + x0] + w01 * pa[y0 * 7 + x1] +
                  w10 * pa[y1 * 7 + x0] + w11 * pa[y1 * 7 + x1];
    const float* pn = na_b + (h * NA + a) * 49;
    float up_na = w00 * pn[y0 * 7 + x0] + w01 * pn[y0 * 7 + x1] +
                  w10 * pn[y1 * 7 + x0] + w11 * pn[y1 * 7 + x1];
    float pb = up_an + ah_b[(h * NA + a) * 56 + y] + aw_b[(h * NA + a) * 56 + x];
    pos_bias[((size_t)(h * NAP + a)) * NTOK + n] = pb;
    float ab = up_na + ha_b[(h * 56 + y) * NA + a] + wa_b[(h * 56 + x) * NA + a];
    agent_bias[((size_t)(h * NAP + a)) * NTOK + n] = ab;
  }
  for (int a = NA; a < NAP; ++a)
    pos_bias[((size_t)(h * NAP + a)) * NTOK + n] = 0.f;
}

// ---------------- generic f16 MFMA GEMM: C[M,N] = A[M,256] * Bw[N,256]^T ----------------
// BM=BN=128, BK=32, 256 threads (4 waves, 2x2 of 64x64)
// LDS: row stride 80 bytes (64B data + 16B pad) -> max 2-way bank conflict.
// AF32: A is float32 (converted to f16 during staging).
template <bool PROJ, bool AF32>
__global__ __launch_bounds__(256) void k_gemm(const void* __restrict__ Av, const f16* __restrict__ Bw,
                                              f16* __restrict__ Cf16, float* __restrict__ Cf32,
                                              const float* __restrict__ bias, int N) {
  __shared__ __align__(16) char lds[2 * 128 * 80];
  int n0 = blockIdx.x * 128;
  int m0 = blockIdx.y * 128;
  int tid = threadIdx.x, w = tid >> 6, l = tid & 63, lr = l & 15, lg = l >> 4;
  int wm = w >> 1, wn = w & 1;
  f32x4 acc[4][4] = {};
  const char* Bbase = (const char*)Bw + (size_t)n0 * 512;
  for (int k0 = 0; k0 < 256; k0 += 32) {
    if (AF32) {
      const float* Af = (const float*)Av;
#pragma unroll
      for (int rd = 0; rd < 2; ++rd) {
        int c = rd * 256 + tid;        // 512 chunks; each = 8 floats -> 8 f16
        int r = c >> 2, q = c & 3;
        const float* src = Af + (size_t)(m0 + r) * 256 + k0 + q * 8;
        float4 v0 = *(const float4*)src;
        float4 v1 = *(const float4*)(src + 4);
        half8 hv = {(f16)v0.x, (f16)v0.y, (f16)v0.z, (f16)v0.w,
                    (f16)v1.x, (f16)v1.y, (f16)v1.z, (f16)v1.w};
        *(half8*)(lds + r * 80 + q * 16) = hv;
      }
    } else {
      const char* Abase = (const char*)Av + (size_t)m0 * 512;
#pragma unroll
      for (int rd = 0; rd < 2; ++rd) {
        int c = rd * 256 + tid;
        int r = c >> 2, koff = (c & 3) * 16;
        *(half8*)(lds + r * 80 + koff) = *(const half8*)(Abase + (size_t)r * 512 + k0 * 2 + koff);
      }
    }
#pragma unroll
    for (int rd = 0; rd < 2; ++rd) {
      int c = rd * 256 + tid;
      int r = c >> 2, koff = (c & 3) * 16;
      *(half8*)(lds + 10240 + r * 80 + koff) = *(const half8*)(Bbase + (size_t)r * 512 + k0 * 2 + koff);
    }
    __syncthreads();
    half8 af[4], bf[4];
#pragma unroll
    for (int mt = 0; mt < 4; ++mt) {
      int row = wm * 64 + mt * 16 + lr;
      af[mt] = *(const half8*)(lds + row * 80 + lg * 16);
    }
#pragma unroll
    for (int nt = 0; nt < 4; ++nt) {
      int row = wn * 64 + nt * 16 + lr;
      bf[nt] = *(const half8*)(lds + 10240 + row * 80 + lg * 16);
    }
#pragma unroll
    for (int mt = 0; mt < 4; ++mt)
#pragma unroll
      for (int nt = 0; nt < 4; ++nt)
        acc[mt][nt] = mfma16(af[mt], bf[nt], acc[mt][nt]);
    __syncthreads();
  }
#pragma unroll
  for (int mt = 0; mt < 4; ++mt)
#pragma unroll
    for (int nt = 0; nt < 4; ++nt)
#pragma unroll
      for (int r = 0; r < 4; ++r) {
        int m = m0 + wm * 64 + mt * 16 + lg * 4 + r;
        int n = n0 + wn * 64 + nt * 16 + lr;
        if (PROJ)
          Cf32[(size_t)m * N + n] = acc[mt][nt][r] + bias[n];
        else
          Cf16[(size_t)m * N + n] = (f16)acc[mt][nt][r];
      }
}

// ---------------- agent pooling (scaled) + token means ----------------
__global__ __launch_bounds__(256) void k_pool_tw(const f16* qkv, f16* agent, float* tw) {
  int bh = blockIdx.x, b = bh >> 3, h = bh & 7;
  int tid = threadIdx.x;
  for (int s = tid; s < NAP * 32; s += 256) {
    int a = s >> 5, d = s & 31;
    float val = 0.f;
    if (a < NA) {
      int dh = a / 7, dwi = a - dh * 7;
      float sum = 0.f;
      for (int i = 0; i < 8; ++i)
        for (int j = 0; j < 8; ++j) {
          int n = (dh * 8 + i) * 56 + dwi * 8 + j;
          sum += (float)qkv[((size_t)(b * NTOK + n)) * QLD + h * 32 + d];
        }
      val = sum * (SCALE / 64.f);
    }
    agent[(size_t)bh * NAP * 32 + s] = (f16)val;
  }
  for (int n = tid; n < NTOK; n += 256) {
    const half8* qp = (const half8*)(qkv + ((size_t)(b * NTOK + n)) * QLD + h * 32);
    float sum = 0.f;
#pragma unroll
    for (int j = 0; j < 4; ++j) {
      half8 v = qp[j];
#pragma unroll
      for (int e = 0; e < 8; ++e) sum += (float)v[e];
    }
    tw[(size_t)bh * NTOK + n] = sum * (1.f / 32.f);
  }
}

// ---------------- exact top-k (desc value, asc index) via bitonic sort ----------------
__global__ __launch_bounds__(1024) void k_topk(const float* tw, int* topidx) {
  __shared__ unsigned long long keys[4096];
  int bh = blockIdx.x, tid = threadIdx.x;
  const float* p = tw + (size_t)bh * NTOK;
  for (int s = tid; s < 4096; s += 1024) {
    float v = (s < NTOK) ? p[s] : -1e30f;
    unsigned ub = __float_as_uint(v);
    ub = (ub & 0x80000000u) ? ~ub : (ub | 0x80000000u);
    unsigned low = (s < NTOK) ? ~(unsigned)s : 0u;
    keys[s] = ((unsigned long long)ub << 32) | low;
  }
  for (int k = 2; k <= 4096; k <<= 1)
    for (int j = k >> 1; j > 0; j >>= 1) {
      __syncthreads();
      for (int i = tid; i < 4096; i += 1024) {
        int ixj = i ^ j;
        if (ixj > i) {
          unsigned long long a = keys[i], c = keys[ixj];
          bool lt = a < c;
          bool descRegion = ((i & k) == 0);
          if (lt == descRegion) { keys[i] = c; keys[ixj] = a; }
        }
      }
    }
  __syncthreads();
  for (int t = tid; t < TTOP; t += 1024)
    topidx[(size_t)bh * TTOP + t] = (int)(~(unsigned)keys[t]);
}

// ---------------- v transpose: vt[bh][d=32][n=3136] ----------------
__global__ __launch_bounds__(256) void k_vt(const f16* qkv, f16* vt) {
  __shared__ f16 t[64][33];
  int bh = blockIdx.y, b = bh >> 3, h = bh & 7;
  int n0 = blockIdx.x * 64;
  int tid = threadIdx.x;
  for (int s = tid; s < 64 * 32; s += 256) {
    int nl = s >> 5, d = s & 31;
    t[nl][d] = qkv[((size_t)(b * NTOK + n0 + nl)) * QLD + 512 + h * 32 + d];
  }
  __syncthreads();
  for (int s = tid; s < 64 * 32; s += 256) {
    int d = s >> 6, nl = s & 63;
    vt[((size_t)(bh * 32 + d)) * NTOK + n0 + nl] = t[nl][d];
  }
}

// ---------------- fused agent attention: softmax_n(agent_s . k^T + bias) @ v ----------------
__global__ __launch_bounds__(256) void k_flash(const f16* qkv, const f16* agent, const f16* vt,
                                               const float* pos_bias, float* agent_v) {
  __shared__ __align__(16) f16 pbuf[4][64][40];
  __shared__ float ored[64][33];
  __shared__ float rssum[64];
  int bh = blockIdx.x, b = bh >> 3, h = bh & 7;
  int tid = threadIdx.x, w = tid >> 6, l = tid & 63, lr = l & 15, lg = l >> 4;
  half8 afrag[4];
#pragma unroll
  for (int mt = 0; mt < 4; ++mt)
    afrag[mt] = *(const half8*)(agent + ((size_t)bh * 64 + mt * 16 + lr) * 32 + lg * 8);
  f32x4 o[4][2] = {};
  float rs[4][4] = {};
  const f16* kbase = qkv + (size_t)b * NTOK * QLD + 256 + h * 32;
  const f16* vtb = vt + (size_t)bh * 32 * NTOK;
  const float* pbb = pos_bias + (size_t)h * NAP * NTOK;
  f32x4 zero = {};
  for (int n0 = w * 32; n0 < NTOK; n0 += 128) {
#pragma unroll
    for (int t2 = 0; t2 < 2; ++t2) {
      int nc = n0 + t2 * 16;
      half8 kf = *(const half8*)(kbase + (size_t)(nc + lr) * QLD + lg * 8);
#pragma unroll
      for (int mt = 0; mt < 4; ++mt) {
        f32x4 s = mfma16(afrag[mt], kf, zero);
#pragma unroll
        for (int r = 0; r < 4; ++r) {
          int a = mt * 16 + lg * 4 + r;
          float pv = __expf(s[r] + pbb[(size_t)a * NTOK + nc + lr]);
          rs[mt][r] += pv;
          pbuf[w][a][t2 * 16 + lr] = (f16)pv;
        }
      }
    }
    half8 pf[4];
#pragma unroll
    for (int mt = 0; mt < 4; ++mt)
      pf[mt] = *(const half8*)(&pbuf[w][mt * 16 + lr][lg * 8]);
#pragma unroll
    for (int dt = 0; dt < 2; ++dt) {
      half8 vf = *(const half8*)(vtb + (size_t)(dt * 16 + lr) * NTOK + n0 + lg * 8);
#pragma unroll
      for (int mt = 0; mt < 4; ++mt)
        o[mt][dt] = mfma16(pf[mt], vf, o[mt][dt]);
    }
  }
#pragma unroll
  for (int mt = 0; mt < 4; ++mt)
#pragma unroll
    for (int r = 0; r < 4; ++r) {
      float v = rs[mt][r];
      for (int off = 1; off < 16; off <<= 1) v += __shfl_xor(v, off, 64);
      rs[mt][r] = v;
    }
  for (int s = tid; s < 64 * 33; s += 256) ((float*)ored)[s] = 0.f;
  if (tid < 64) rssum[tid] = 0.f;
  __syncthreads();
  for (int ww = 0; ww < 4; ++ww) {
    if (w == ww) {
      if (lr == 0)
#pragma unroll
        for (int mt = 0; mt < 4; ++mt)
#pragma unroll
          for (int r = 0; r < 4; ++r) rssum[mt * 16 + lg * 4 + r] += rs[mt][r];
#pragma unroll
      for (int mt = 0; mt < 4; ++mt)
#pragma unroll
        for (int dt = 0; dt < 2; ++dt)
#pragma unroll
          for (int r = 0; r < 4; ++r)
            ored[mt * 16 + lg * 4 + r][dt * 16 + lr] += o[mt][dt][r];
    }
    __syncthreads();
  }
  for (int s = tid; s < NA * 32; s += 256) {
    int a = s >> 5, d = s & 31;
    agent_v[(size_t)bh * NA * 32 + s] = ored[a][d] / rssum[a];
  }
}

// ---------------- fused: q2 (gathered) -> resize -> softmax_a -> @agent_v, + dwconv ----------------
// q2buf f16 stride 76 (2-way conflicts = free); agent_bias transposed (coalesced);
// single-pass softmax (logits bounded ~|1|); conv from vt (coalesced).
__global__ __launch_bounds__(256) void k_second(const f16* qkv, const f16* agent, const int* topidx,
                                                const float* agent_v, const float* agent_bias,
                                                const float* dwc_w, const float* dwc_b,
                                                const f16* vt, f16* pre) {
  __shared__ __align__(16) f16 q2buf[160][76];
  __shared__ float av[NA][32];
  __shared__ float wconv[9][32];
  __shared__ float bconv[32];
  int chunk = blockIdx.x, bh = blockIdx.y, b = bh >> 3, h = bh & 7;
  int tid = threadIdx.x, w = tid >> 6, l = tid & 63, lr = l & 15, lg = l >> 4;
  for (int s = tid; s < NA * 32; s += 256) ((float*)av)[s] = agent_v[(size_t)bh * NA * 32 + s];
  for (int s = tid; s < 32 * 9; s += 256) {
    int d = s / 9, t = s - d * 9;           // dwc_w layout [c][t]
    wconv[t][d] = dwc_w[(size_t)(h * 32 + d) * 9 + t];
  }
  if (tid < 32) bconv[tid] = dwc_b[h * 32 + tid];
  half8 bfrag[4];
#pragma unroll
  for (int nt = 0; nt < 4; ++nt)
    bfrag[nt] = *(const half8*)(agent + ((size_t)bh * 64 + nt * 16 + lr) * 32 + lg * 8);
  int jbase = chunk * 128 - 16;
  f32x4 zero = {};
  for (int mt = w; mt < 10; mt += 4) {
    int j = jbase + mt * 16 + lr;
    int jc = min(max(j, 0), TTOP - 1);
    int tok = topidx[(size_t)bh * TTOP + jc];
    half8 qf = *(const half8*)(qkv + ((size_t)(b * NTOK + tok)) * QLD + h * 32 + lg * 8);
#pragma unroll
    for (int nt = 0; nt < 4; ++nt) {
      f32x4 s = mfma16(qf, bfrag[nt], zero);
#pragma unroll
      for (int r = 0; r < 4; ++r)
        q2buf[mt * 16 + lg * 4 + r][nt * 16 + lr] = (f16)s[r];
    }
  }
  __syncthreads();
  int i = chunk * 256 + tid;
  if (i >= NTOK) return;
  int y = i / 56, x = i - y * 56;
  int hi = i >> 1;
  int jA, jB; float wA, wB;
  if (i & 1) { jA = hi; jB = hi + 1; wA = 0.75f; wB = 0.25f; }
  else       { jA = hi - 1; jB = hi; wA = 0.25f; wB = 0.75f; }
  jA = min(max(jA, 0), TTOP - 1);
  jB = min(max(jB, 0), TTOP - 1);
  int lA = jA - jbase, lB = jB - jbase;
  const float* ab = agent_bias + (size_t)h * NAP * NTOK + i;   // [h][a][n], coalesced in n
  float acc[32] = {};
  float ssum = 0.f;
  for (int a = 0; a < NA; ++a) {
    float v = wA * (float)q2buf[lA][a] + wB * (float)q2buf[lB][a] + ab[(size_t)a * NTOK];
    float pv = __expf(v);
    ssum += pv;
    const float4* avr = (const float4*)av[a];
#pragma unroll
    for (int d4 = 0; d4 < 8; ++d4) {
      float4 v4 = avr[d4];
      acc[d4 * 4 + 0] += pv * v4.x;
      acc[d4 * 4 + 1] += pv * v4.y;
      acc[d4 * 4 + 2] += pv * v4.z;
      acc[d4 * 4 + 3] += pv * v4.w;
    }
  }
  float inv = 1.f / ssum;
  // hoist conv tap addresses
  const f16* vtb = vt + (size_t)bh * 32 * NTOK;
  int nns[9]; bool ok[9];
#pragma unroll
  for (int ky = 0; ky < 3; ++ky)
#pragma unroll
    for (int kx = 0; kx < 3; ++kx) {
      int yy = y + ky - 1, xx = x + kx - 1;
      int t = ky * 3 + kx;
      ok[t] = (yy >= 0 && yy < 56 && xx >= 0 && xx < 56);
      nns[t] = yy * 56 + xx;
    }
#pragma unroll 4
  for (int d = 0; d < 32; ++d) {
    float cv = bconv[d];
    const f16* vrow = vtb + (size_t)d * NTOK;
#pragma unroll
    for (int t = 0; t < 9; ++t)
      if (ok[t]) cv += wconv[t][d] * (float)vrow[nns[t]];
    acc[d] = acc[d] * inv + cv;
  }
  f16* op = pre + ((size_t)(b * NTOK + i)) * 256 + h * 32;
#pragma unroll
  for (int d = 0; d < 32; ++d) op[d] = (f16)acc[d];
}

extern "C" void kernel_launch(void* const* d_in, const int* in_sizes, int n_in,
                              void* d_out, int out_size, void* d_ws, size_t ws_size,
                              hipStream_t stream) {
  const float* x     = (const float*)d_in[0];
  const float* Wq    = (const float*)d_in[3];
  const float* Wkv   = (const float*)d_in[4];
  const float* Wproj = (const float*)d_in[5];
  const float* bproj = (const float*)d_in[6];
  const float* dwc_w = (const float*)d_in[7];
  const float* dwc_b = (const float*)d_in[8];
  const float* an_b  = (const float*)d_in[9];
  const float* na_b  = (const float*)d_in[10];
  const float* ah_b  = (const float*)d_in[11];
  const float* aw_b  = (const float*)d_in[12];
  const float* ha_b  = (const float*)d_in[13];
  const float* wa_b  = (const float*)d_in[14];

  char* ws = (char*)d_ws;
  size_t off = 0;
  auto alloc = [&](size_t bytes) {
    void* p = ws + off;
    off = (off + bytes + 255) & ~(size_t)255;
    return p;
  };
  f16* wqkv    = (f16*)alloc((size_t)768 * 256 * 2);
  f16* wproj   = (f16*)alloc((size_t)256 * 256 * 2);
  f16* qkv     = (f16*)alloc((size_t)50176 * 768 * 2);
  float* posb  = (float*)alloc((size_t)8 * NAP * NTOK * 4);
  float* agb   = (float*)alloc((size_t)8 * NAP * NTOK * 4);
  f16* agent   = (f16*)alloc((size_t)128 * NAP * 32 * 2);
  float* tw    = (float*)alloc((size_t)128 * NTOK * 4);
  int* topidx  = (int*)alloc((size_t)128 * TTOP * 4);
  f16* vt      = (f16*)alloc((size_t)128 * 32 * NTOK * 2);
  float* agv   = (float*)alloc((size_t)128 * NA * 32 * 4);
  f16* pre     = (f16*)alloc((size_t)50176 * 256 * 2);

  k_prep_w<<<1024, 256, 0, stream>>>(Wq, Wkv, Wproj, wqkv, wproj);
  k_bias<<<dim3(13, 8), 256, 0, stream>>>(an_b, na_b, ah_b, aw_b, ha_b, wa_b, posb, agb);
  k_gemm<false, true><<<dim3(6, 392), 256, 0, stream>>>(x, wqkv, qkv, nullptr, nullptr, 768);
  k_pool_tw<<<128, 256, 0, stream>>>(qkv, agent, tw);
  k_topk<<<128, 1024, 0, stream>>>(tw, topidx);
  k_vt<<<dim3(49, 128), 256, 0, stream>>>(qkv, vt);
  k_flash<<<128, 256, 0, stream>>>(qkv, agent, vt, posb, agv);
  k_second<<<dim3(13, 128), 256, 0, stream>>>(qkv, agent, topidx, agv, agb, dwc_w, dwc_b, vt, pre);
  k_gemm<true, false><<<dim3(2, 392), 256, 0, stream>>>(pre, wproj, nullptr, (float*)d_out, bproj, 256);
}

// Round 4
// 360.009 us; speedup vs baseline: 1.3719x; 1.1952x over previous
//
#include <hip/hip_runtime.h>
#include <stdint.h>

typedef _Float16 f16;
typedef _Float16 half8 __attribute__((ext_vector_type(8)));
typedef float f32x4 __attribute__((ext_vector_type(4)));

#define NBATCH 16
#define NTOK 3136
#define NH 8
#define NA 49
#define NAP 64
#define TTOP 1568
#define QLD 768
#define NTILES 196          // NTOK/16
#define PBH 200704          // NTILES*8*16*8 f16 elements per bh
#define SCALE 0.17677669529663687f

__device__ __forceinline__ f32x4 mfma16(half8 a, half8 b, f32x4 c) {
  return __builtin_amdgcn_mfma_f32_16x16x32_f16(a, b, c, 0, 0, 0);
}

// ---------------- weight conversion ----------------
__global__ __launch_bounds__(256) void k_prep_w(const float* Wq, const float* Wkv, const float* Wproj,
                                                f16* wqkv, f16* wproj) {
  int total1 = 768 * 256;
  int total = total1 + 256 * 256;
  for (int i = blockIdx.x * 256 + threadIdx.x; i < total; i += gridDim.x * 256) {
    if (i < total1) {
      int j = i >> 8, k = i & 255;
      float v = (j < 256) ? Wq[j * 256 + k] : Wkv[(j - 256) * 256 + k];
      wqkv[i] = (f16)v;
    } else {
      int i2 = i - total1;
      wproj[i2] = (f16)Wproj[i2];
    }
  }
}

// ---------------- bias precompute ----------------
__global__ __launch_bounds__(256) void k_bias(const float* an_b, const float* na_b,
                                              const float* ah_b, const float* aw_b,
                                              const float* ha_b, const float* wa_b,
                                              float* pos_bias, float* agent_bias) {
  int n = blockIdx.x * 256 + threadIdx.x;
  int h = blockIdx.y;
  if (n >= NTOK) return;
  int y = n / 56, x = n - y * 56;
  float py = (y + 0.5f) * 0.125f - 0.5f;
  float px = (x + 0.5f) * 0.125f - 0.5f;
  int iy0 = (int)floorf(py); float fy = py - (float)iy0;
  int ix0 = (int)floorf(px); float fx = px - (float)ix0;
  int y0 = max(iy0, 0), y1 = min(iy0 + 1, 6);
  int x0 = max(ix0, 0), x1 = min(ix0 + 1, 6);
  float w00 = (1.f - fy) * (1.f - fx), w01 = (1.f - fy) * fx;
  float w10 = fy * (1.f - fx), w11 = fy * fx;
  for (int a = 0; a < NA; ++a) {
    const float* pa = an_b + (h * NA + a) * 49;
    float up_an = w00 * pa[y0 * 7 + x0] + w01 * pa[y0 * 7 + x1] +
                  w10 * pa[y1 * 7 + x0] + w11 * pa[y1 * 7 + x1];
    const float* pn = na_b + (h * NA + a) * 49;
    float up_na = w00 * pn[y0 * 7 + x0] + w01 * pn[y0 * 7 + x1] +
                  w10 * pn[y1 * 7 + x0] + w11 * pn[y1 * 7 + x1];
    float pb = up_an + ah_b[(h * NA + a) * 56 + y] + aw_b[(h * NA + a) * 56 + x];
    pos_bias[((size_t)(h * NAP + a)) * NTOK + n] = pb;
    float ab = up_na + ha_b[(h * 56 + y) * NA + a] + wa_b[(h * 56 + x) * NA + a];
    agent_bias[((size_t)(h * NAP + a)) * NTOK + n] = ab;
  }
  for (int a = NA; a < NAP; ++a)
    pos_bias[((size_t)(h * NAP + a)) * NTOK + n] = 0.f;
}

// ---------------- generic f16 MFMA GEMM: C[M,N] = A[M,256] * Bw[N,256]^T ----------------
template <bool PROJ, bool AF32>
__global__ __launch_bounds__(256) void k_gemm(const void* __restrict__ Av, const f16* __restrict__ Bw,
                                              f16* __restrict__ Cf16, float* __restrict__ Cf32,
                                              const float* __restrict__ bias, int N) {
  __shared__ __align__(16) char lds[2 * 128 * 80];
  int n0 = blockIdx.x * 128;
  int m0 = blockIdx.y * 128;
  int tid = threadIdx.x, w = tid >> 6, l = tid & 63, lr = l & 15, lg = l >> 4;
  int wm = w >> 1, wn = w & 1;
  f32x4 acc[4][4] = {};
  const char* Bbase = (const char*)Bw + (size_t)n0 * 512;
  for (int k0 = 0; k0 < 256; k0 += 32) {
    if (AF32) {
      const float* Af = (const float*)Av;
#pragma unroll
      for (int rd = 0; rd < 2; ++rd) {
        int c = rd * 256 + tid;
        int r = c >> 2, q = c & 3;
        const float* src = Af + (size_t)(m0 + r) * 256 + k0 + q * 8;
        float4 v0 = *(const float4*)src;
        float4 v1 = *(const float4*)(src + 4);
        half8 hv = {(f16)v0.x, (f16)v0.y, (f16)v0.z, (f16)v0.w,
                    (f16)v1.x, (f16)v1.y, (f16)v1.z, (f16)v1.w};
        *(half8*)(lds + r * 80 + q * 16) = hv;
      }
    } else {
      const char* Abase = (const char*)Av + (size_t)m0 * 512;
#pragma unroll
      for (int rd = 0; rd < 2; ++rd) {
        int c = rd * 256 + tid;
        int r = c >> 2, koff = (c & 3) * 16;
        *(half8*)(lds + r * 80 + koff) = *(const half8*)(Abase + (size_t)r * 512 + k0 * 2 + koff);
      }
    }
#pragma unroll
    for (int rd = 0; rd < 2; ++rd) {
      int c = rd * 256 + tid;
      int r = c >> 2, koff = (c & 3) * 16;
      *(half8*)(lds + 10240 + r * 80 + koff) = *(const half8*)(Bbase + (size_t)r * 512 + k0 * 2 + koff);
    }
    __syncthreads();
    half8 af[4], bf[4];
#pragma unroll
    for (int mt = 0; mt < 4; ++mt) {
      int row = wm * 64 + mt * 16 + lr;
      af[mt] = *(const half8*)(lds + row * 80 + lg * 16);
    }
#pragma unroll
    for (int nt = 0; nt < 4; ++nt) {
      int row = wn * 64 + nt * 16 + lr;
      bf[nt] = *(const half8*)(lds + 10240 + row * 80 + lg * 16);
    }
#pragma unroll
    for (int mt = 0; mt < 4; ++mt)
#pragma unroll
      for (int nt = 0; nt < 4; ++nt)
        acc[mt][nt] = mfma16(af[mt], bf[nt], acc[mt][nt]);
    __syncthreads();
  }
#pragma unroll
  for (int mt = 0; mt < 4; ++mt)
#pragma unroll
    for (int nt = 0; nt < 4; ++nt)
#pragma unroll
      for (int r = 0; r < 4; ++r) {
        int m = m0 + wm * 64 + mt * 16 + lg * 4 + r;
        int n = n0 + wn * 64 + nt * 16 + lr;
        if (PROJ)
          Cf32[(size_t)m * N + n] = acc[mt][nt][r] + bias[n];
        else
          Cf16[(size_t)m * N + n] = (f16)acc[mt][nt][r];
      }
}

// ---------------- agent pooling (scaled) + token means ----------------
__global__ __launch_bounds__(256) void k_pool_tw(const f16* qkv, f16* agent, float* tw) {
  int bh = blockIdx.x, b = bh >> 3, h = bh & 7;
  int tid = threadIdx.x;
  for (int s = tid; s < NAP * 32; s += 256) {
    int a = s >> 5, d = s & 31;
    float val = 0.f;
    if (a < NA) {
      int dh = a / 7, dwi = a - dh * 7;
      float sum = 0.f;
      for (int i = 0; i < 8; ++i)
        for (int j = 0; j < 8; ++j) {
          int n = (dh * 8 + i) * 56 + dwi * 8 + j;
          sum += (float)qkv[((size_t)(b * NTOK + n)) * QLD + h * 32 + d];
        }
      val = sum * (SCALE / 64.f);
    }
    agent[(size_t)bh * NAP * 32 + s] = (f16)val;
  }
  for (int n = tid; n < NTOK; n += 256) {
    const half8* qp = (const half8*)(qkv + ((size_t)(b * NTOK + n)) * QLD + h * 32);
    float sum = 0.f;
#pragma unroll
    for (int j = 0; j < 4; ++j) {
      half8 v = qp[j];
#pragma unroll
      for (int e = 0; e < 8; ++e) sum += (float)v[e];
    }
    tw[(size_t)bh * NTOK + n] = sum * (1.f / 32.f);
  }
}

// ---------------- exact top-k (desc value, asc index) via bitonic sort ----------------
__global__ __launch_bounds__(1024) void k_topk(const float* tw, int* topidx) {
  __shared__ unsigned long long keys[4096];
  int bh = blockIdx.x, tid = threadIdx.x;
  const float* p = tw + (size_t)bh * NTOK;
  for (int s = tid; s < 4096; s += 1024) {
    float v = (s < NTOK) ? p[s] : -1e30f;
    unsigned ub = __float_as_uint(v);
    ub = (ub & 0x80000000u) ? ~ub : (ub | 0x80000000u);
    unsigned low = (s < NTOK) ? ~(unsigned)s : 0u;
    keys[s] = ((unsigned long long)ub << 32) | low;
  }
  for (int k = 2; k <= 4096; k <<= 1)
    for (int j = k >> 1; j > 0; j >>= 1) {
      __syncthreads();
      for (int i = tid; i < 4096; i += 1024) {
        int ixj = i ^ j;
        if (ixj > i) {
          unsigned long long a = keys[i], c = keys[ixj];
          bool lt = a < c;
          bool descRegion = ((i & k) == 0);
          if (lt == descRegion) { keys[i] = c; keys[ixj] = a; }
        }
      }
    }
  __syncthreads();
  for (int t = tid; t < TTOP; t += 1024)
    topidx[(size_t)bh * TTOP + t] = (int)(~(unsigned)keys[t]);
}

// ---------------- v transpose: vt[bh][d=32][n=3136] ----------------
__global__ __launch_bounds__(256) void k_vt(const f16* qkv, f16* vt) {
  __shared__ f16 t[64][33];
  int bh = blockIdx.y, b = bh >> 3, h = bh & 7;
  int n0 = blockIdx.x * 64;
  int tid = threadIdx.x;
  for (int s = tid; s < 64 * 32; s += 256) {
    int nl = s >> 5, d = s & 31;
    t[nl][d] = qkv[((size_t)(b * NTOK + n0 + nl)) * QLD + 512 + h * 32 + d];
  }
  __syncthreads();
  for (int s = tid; s < 64 * 32; s += 256) {
    int d = s >> 6, nl = s & 63;
    vt[((size_t)(bh * 32 + d)) * NTOK + n0 + nl] = t[nl][d];
  }
}

// ---------------- fused agent attention: softmax_n(agent_s . k^T + bias) @ v ----------------
__global__ __launch_bounds__(256) void k_flash(const f16* qkv, const f16* agent, const f16* vt,
                                               const float* pos_bias, float* agent_v) {
  __shared__ __align__(16) f16 pbuf[4][64][40];
  __shared__ float ored[64][33];
  __shared__ float rssum[64];
  int bh = blockIdx.x, b = bh >> 3, h = bh & 7;
  int tid = threadIdx.x, w = tid >> 6, l = tid & 63, lr = l & 15, lg = l >> 4;
  half8 afrag[4];
#pragma unroll
  for (int mt = 0; mt < 4; ++mt)
    afrag[mt] = *(const half8*)(agent + ((size_t)bh * 64 + mt * 16 + lr) * 32 + lg * 8);
  f32x4 o[4][2] = {};
  float rs[4][4] = {};
  const f16* kbase = qkv + (size_t)b * NTOK * QLD + 256 + h * 32;
  const f16* vtb = vt + (size_t)bh * 32 * NTOK;
  const float* pbb = pos_bias + (size_t)h * NAP * NTOK;
  f32x4 zero = {};
  for (int n0 = w * 32; n0 < NTOK; n0 += 128) {
#pragma unroll
    for (int t2 = 0; t2 < 2; ++t2) {
      int nc = n0 + t2 * 16;
      half8 kf = *(const half8*)(kbase + (size_t)(nc + lr) * QLD + lg * 8);
#pragma unroll
      for (int mt = 0; mt < 4; ++mt) {
        f32x4 s = mfma16(afrag[mt], kf, zero);
#pragma unroll
        for (int r = 0; r < 4; ++r) {
          int a = mt * 16 + lg * 4 + r;
          float pv = __expf(s[r] + pbb[(size_t)a * NTOK + nc + lr]);
          rs[mt][r] += pv;
          pbuf[w][a][t2 * 16 + lr] = (f16)pv;
        }
      }
    }
    half8 pf[4];
#pragma unroll
    for (int mt = 0; mt < 4; ++mt)
      pf[mt] = *(const half8*)(&pbuf[w][mt * 16 + lr][lg * 8]);
#pragma unroll
    for (int dt = 0; dt < 2; ++dt) {
      half8 vf = *(const half8*)(vtb + (size_t)(dt * 16 + lr) * NTOK + n0 + lg * 8);
#pragma unroll
      for (int mt = 0; mt < 4; ++mt)
        o[mt][dt] = mfma16(pf[mt], vf, o[mt][dt]);
    }
  }
#pragma unroll
  for (int mt = 0; mt < 4; ++mt)
#pragma unroll
    for (int r = 0; r < 4; ++r) {
      float v = rs[mt][r];
      for (int off = 1; off < 16; off <<= 1) v += __shfl_xor(v, off, 64);
      rs[mt][r] = v;
    }
  for (int s = tid; s < 64 * 33; s += 256) ((float*)ored)[s] = 0.f;
  if (tid < 64) rssum[tid] = 0.f;
  __syncthreads();
  for (int ww = 0; ww < 4; ++ww) {
    if (w == ww) {
      if (lr == 0)
#pragma unroll
        for (int mt = 0; mt < 4; ++mt)
#pragma unroll
          for (int r = 0; r < 4; ++r) rssum[mt * 16 + lg * 4 + r] += rs[mt][r];
#pragma unroll
      for (int mt = 0; mt < 4; ++mt)
#pragma unroll
        for (int dt = 0; dt < 2; ++dt)
#pragma unroll
          for (int r = 0; r < 4; ++r)
            ored[mt * 16 + lg * 4 + r][dt * 16 + lr] += o[mt][dt][r];
    }
    __syncthreads();
  }
  for (int s = tid; s < NA * 32; s += 256) {
    int a = s >> 5, d = s & 31;
    agent_v[(size_t)bh * NA * 32 + s] = ored[a][d] / rssum[a];
  }
}

// ---------------- k_psm: q2 gather-MFMA -> resize -> exp -> P (fragment layout) + ssum ----------------
// P layout per bh: [tile(196)][kchunk(8)][lane(16)][8] f16  (A-frag coalesced for k_out)
__global__ __launch_bounds__(256) void k_psm(const f16* qkv, const f16* agent, const int* topidx,
                                             const float* agent_bias, f16* P, float* ssumg) {
  __shared__ __align__(16) f16 q2buf[144][88];
  int chunk = blockIdx.x, bh = blockIdx.y, b = bh >> 3, h = bh & 7;
  int tid = threadIdx.x, w = tid >> 6, l = tid & 63, lr = l & 15, lg = l >> 4;
  half8 bfrag[4];
#pragma unroll
  for (int nt = 0; nt < 4; ++nt)
    bfrag[nt] = *(const half8*)(agent + ((size_t)bh * 64 + nt * 16 + lr) * 32 + lg * 8);
  int jbase = chunk * 128 - 8;
  f32x4 zero = {};
  for (int mt = w; mt < 9; mt += 4) {
    int j = jbase + mt * 16 + lr;
    int jc = min(max(j, 0), TTOP - 1);
    int tok = topidx[(size_t)bh * TTOP + jc];
    half8 qf = *(const half8*)(qkv + ((size_t)(b * NTOK + tok)) * QLD + h * 32 + lg * 8);
#pragma unroll
    for (int nt = 0; nt < 4; ++nt) {
      f32x4 s = mfma16(qf, bfrag[nt], zero);
#pragma unroll
      for (int r = 0; r < 4; ++r)
        q2buf[mt * 16 + lg * 4 + r][nt * 16 + lr] = (f16)s[r];
    }
  }
  __syncthreads();
  int g = chunk * 256 + tid;
  if (g >= NTOK) return;
  int hi = g >> 1;
  int jA, jB; float wAq, wBq;
  if (g & 1) { jA = hi; jB = hi + 1; wAq = 0.75f; wBq = 0.25f; }
  else       { jA = hi - 1; jB = hi; wAq = 0.25f; wBq = 0.75f; }
  jA = min(max(jA, 0), TTOP - 1);
  jB = min(max(jB, 0), TTOP - 1);
  int lA = jA - jbase, lB = jB - jbase;
  const float* ab = agent_bias + (size_t)h * NAP * NTOK + g;
  f16* Pb = P + (size_t)bh * PBH;
  int tile = g >> 4, lrr = g & 15;
  float ssum = 0.f;
#pragma unroll
  for (int c = 0; c < 7; ++c) {
    half8 a8 = *(const half8*)(&q2buf[lA][c * 8]);
    half8 b8 = *(const half8*)(&q2buf[lB][c * 8]);
    half8 o;
#pragma unroll
    for (int e = 0; e < 8; ++e) {
      int a = c * 8 + e;
      float pv = 0.f;
      if (a < NA) {
        float v = wAq * (float)a8[e] + wBq * (float)b8[e] + ab[(size_t)a * NTOK];
        pv = __expf(v);
        ssum += pv;
      }
      o[e] = (f16)pv;
    }
    *(half8*)(Pb + ((size_t)(tile * 8 + c) * 16 + lrr) * 8) = o;
  }
  half8 z = {};
  *(half8*)(Pb + ((size_t)(tile * 8 + 7) * 16 + lrr) * 8) = z;
  ssumg[(size_t)bh * NTOK + g] = ssum;
}

// ---------------- k_out: C = (P @ avT)/ssum  + dwconv, write pre ----------------
__global__ __launch_bounds__(256) void k_out(const f16* P, const float* ssumg, const float* agent_v,
                                             const f16* qkv, const float* dwc_w, const float* dwc_b,
                                             f16* pre) {
  __shared__ __align__(16) f16 avT[32][72];
  __shared__ __align__(16) f16 ctile[256][40];
  __shared__ float wconv[9][32];
  __shared__ float bconv[32];
  int chunk = blockIdx.x, bh = blockIdx.y, b = bh >> 3, h = bh & 7;
  int tid = threadIdx.x, w = tid >> 6, l = tid & 63, lr = l & 15, lg = l >> 4;
  // stage avT (zero-padded a>=49 kills P garbage), wconv, bconv
  for (int s = tid; s < 32 * 64; s += 256) {
    int d = s >> 6, a = s & 63;
    avT[d][a] = (a < NA) ? (f16)agent_v[((size_t)bh * NA + a) * 32 + d] : (f16)0.f;
  }
  for (int s = tid; s < 32 * 9; s += 256) {
    int d = s / 9, t = s - d * 9;
    wconv[t][d] = dwc_w[(size_t)(h * 32 + d) * 9 + t];
  }
  if (tid < 32) bconv[tid] = dwc_b[h * 32 + tid];
  __syncthreads();
  half8 bf[2][2];
#pragma unroll
  for (int nt = 0; nt < 2; ++nt)
#pragma unroll
    for (int ks = 0; ks < 2; ++ks)
      bf[nt][ks] = *(const half8*)(&avT[0][0] + (size_t)(nt * 16 + lr) * 72 + ks * 32 + lg * 8);
  const f16* Pb = P + (size_t)bh * PBH;
#pragma unroll
  for (int mt = 0; mt < 4; ++mt) {
    int tile = chunk * 16 + w * 4 + mt;
    if (tile >= NTILES) continue;
    const f16* Pt = Pb + (size_t)tile * 1024;
    half8 a0 = *(const half8*)(Pt + ((size_t)(0 + lg) * 16 + lr) * 8);
    half8 a1 = *(const half8*)(Pt + ((size_t)(4 + lg) * 16 + lr) * 8);
    f32x4 acc0 = {}, acc1 = {};
    acc0 = mfma16(a0, bf[0][0], acc0);
    acc0 = mfma16(a1, bf[0][1], acc0);
    acc1 = mfma16(a0, bf[1][0], acc1);
    acc1 = mfma16(a1, bf[1][1], acc1);
    int ltrow = (w * 4 + mt) * 16 + lg * 4;
#pragma unroll
    for (int r = 0; r < 4; ++r) {
      float ss = ssumg[(size_t)bh * NTOK + tile * 16 + lg * 4 + r];
      float inv = 1.f / ss;
      ctile[ltrow + r][lr] = (f16)(acc0[r] * inv);
      ctile[ltrow + r][16 + lr] = (f16)(acc1[r] * inv);
    }
  }
  __syncthreads();
  int g = chunk * 256 + tid;
  if (g >= NTOK) return;
  float accd[32];
#pragma unroll
  for (int c = 0; c < 4; ++c) {
    half8 cv = *(const half8*)(&ctile[tid][c * 8]);
#pragma unroll
    for (int e = 0; e < 8; ++e) accd[c * 8 + e] = (float)cv[e] + bconv[c * 8 + e];
  }
  int y = g / 56, x = g - y * 56;
  const f16* vbase = qkv + (size_t)b * NTOK * QLD + 512 + h * 32;
#pragma unroll
  for (int ky = 0; ky < 3; ++ky) {
    int yy = y + ky - 1;
    if (yy < 0 || yy >= 56) continue;
#pragma unroll
    for (int kx = 0; kx < 3; ++kx) {
      int xx = x + kx - 1;
      if (xx < 0 || xx >= 56) continue;
      int t = ky * 3 + kx;
      const f16* vp = vbase + (size_t)(yy * 56 + xx) * QLD;
#pragma unroll
      for (int c = 0; c < 4; ++c) {
        half8 vv = *(const half8*)(vp + c * 8);
#pragma unroll
        for (int e = 0; e < 8; ++e) accd[c * 8 + e] += wconv[t][c * 8 + e] * (float)vv[e];
      }
    }
  }
  f16* op = pre + ((size_t)(b * NTOK + g)) * 256 + h * 32;
#pragma unroll
  for (int c = 0; c < 4; ++c) {
    half8 o;
#pragma unroll
    for (int e = 0; e < 8; ++e) o[e] = (f16)accd[c * 8 + e];
    *(half8*)(op + c * 8) = o;
  }
}

extern "C" void kernel_launch(void* const* d_in, const int* in_sizes, int n_in,
                              void* d_out, int out_size, void* d_ws, size_t ws_size,
                              hipStream_t stream) {
  const float* x     = (const float*)d_in[0];
  const float* Wq    = (const float*)d_in[3];
  const float* Wkv   = (const float*)d_in[4];
  const float* Wproj = (const float*)d_in[5];
  const float* bproj = (const float*)d_in[6];
  const float* dwc_w = (const float*)d_in[7];
  const float* dwc_b = (const float*)d_in[8];
  const float* an_b  = (const float*)d_in[9];
  const float* na_b  = (const float*)d_in[10];
  const float* ah_b  = (const float*)d_in[11];
  const float* aw_b  = (const float*)d_in[12];
  const float* ha_b  = (const float*)d_in[13];
  const float* wa_b  = (const float*)d_in[14];

  char* ws = (char*)d_ws;
  size_t off = 0;
  auto alloc = [&](size_t bytes) {
    void* p = ws + off;
    off = (off + bytes + 255) & ~(size_t)255;
    return p;
  };
  f16* wqkv    = (f16*)alloc((size_t)768 * 256 * 2);
  f16* wproj   = (f16*)alloc((size_t)256 * 256 * 2);
  f16* qkv     = (f16*)alloc((size_t)50176 * 768 * 2);
  float* posb  = (float*)alloc((size_t)8 * NAP * NTOK * 4);
  float* agb   = (float*)alloc((size_t)8 * NAP * NTOK * 4);
  f16* agent   = (f16*)alloc((size_t)128 * NAP * 32 * 2);
  float* tw    = (float*)alloc((size_t)128 * NTOK * 4);
  int* topidx  = (int*)alloc((size_t)128 * TTOP * 4);
  f16* vt      = (f16*)alloc((size_t)128 * 32 * NTOK * 2);
  float* agv   = (float*)alloc((size_t)128 * NA * 32 * 4);
  f16* pre     = (f16*)alloc((size_t)50176 * 256 * 2);
  f16* P       = (f16*)alloc((size_t)128 * PBH * 2);
  float* ssumg = tw;  // tw dead after k_topk

  k_prep_w<<<1024, 256, 0, stream>>>(Wq, Wkv, Wproj, wqkv, wproj);
  k_bias<<<dim3(13, 8), 256, 0, stream>>>(an_b, na_b, ah_b, aw_b, ha_b, wa_b, posb, agb);
  k_gemm<false, true><<<dim3(6, 392), 256, 0, stream>>>(x, wqkv, qkv, nullptr, nullptr, 768);
  k_pool_tw<<<128, 256, 0, stream>>>(qkv, agent, tw);
  k_topk<<<128, 1024, 0, stream>>>(tw, topidx);
  k_vt<<<dim3(49, 128), 256, 0, stream>>>(qkv, vt);
  k_flash<<<128, 256, 0, stream>>>(qkv, agent, vt, posb, agv);
  k_psm<<<dim3(13, 128), 256, 0, stream>>>(qkv, agent, topidx, agb, P, ssumg);
  k_out<<<dim3(13, 128), 256, 0, stream>>>(P, ssumg, agv, qkv, dwc_w, dwc_b, pre);
  k_gemm<true, false><<<dim3(2, 392), 256, 0, stream>>>(pre, wproj, nullptr, (float*)d_out, bproj, 256);
}

// Round 6
// 347.242 us; speedup vs baseline: 1.4223x; 1.0368x over previous
//
#include <hip/hip_runtime.h>
#include <stdint.h>

typedef _Float16 f16;
typedef _Float16 half8 __attribute__((ext_vector_type(8)));
typedef __fp16 fp16x2 __attribute__((ext_vector_type(2)));
typedef float f32x4 __attribute__((ext_vector_type(4)));

#define NBATCH 16
#define NTOK 3136
#define NH 8
#define NA 49
#define NAP 64
#define TTOP 1568
#define QLD 768
#define NTILES 196          // NTOK/16
#define PBH 200704          // NTILES*8*16*8 f16 elements per bh
#define SCALE 0.17677669529663687f

__device__ __forceinline__ f32x4 mfma16(half8 a, half8 b, f32x4 c) {
  return __builtin_amdgcn_mfma_f32_16x16x32_f16(a, b, c, 0, 0, 0);
}

// ---------------- weight conversion ----------------
__global__ __launch_bounds__(256) void k_prep_w(const float* Wq, const float* Wkv, const float* Wproj,
                                                f16* wqkv, f16* wproj) {
  int total1 = 768 * 256;
  int total = total1 + 256 * 256;
  for (int i = blockIdx.x * 256 + threadIdx.x; i < total; i += gridDim.x * 256) {
    if (i < total1) {
      int j = i >> 8, k = i & 255;
      float v = (j < 256) ? Wq[j * 256 + k] : Wkv[(j - 256) * 256 + k];
      wqkv[i] = (f16)v;
    } else {
      int i2 = i - total1;
      wproj[i2] = (f16)Wproj[i2];
    }
  }
}

// ---------------- bias precompute ----------------
__global__ __launch_bounds__(256) void k_bias(const float* an_b, const float* na_b,
                                              const float* ah_b, const float* aw_b,
                                              const float* ha_b, const float* wa_b,
                                              float* pos_bias, float* agent_bias) {
  int n = blockIdx.x * 256 + threadIdx.x;
  int h = blockIdx.y;
  if (n >= NTOK) return;
  int y = n / 56, x = n - y * 56;
  float py = (y + 0.5f) * 0.125f - 0.5f;
  float px = (x + 0.5f) * 0.125f - 0.5f;
  int iy0 = (int)floorf(py); float fy = py - (float)iy0;
  int ix0 = (int)floorf(px); float fx = px - (float)ix0;
  int y0 = max(iy0, 0), y1 = min(iy0 + 1, 6);
  int x0 = max(ix0, 0), x1 = min(ix0 + 1, 6);
  float w00 = (1.f - fy) * (1.f - fx), w01 = (1.f - fy) * fx;
  float w10 = fy * (1.f - fx), w11 = fy * fx;
  for (int a = 0; a < NA; ++a) {
    const float* pa = an_b + (h * NA + a) * 49;
    float up_an = w00 * pa[y0 * 7 + x0] + w01 * pa[y0 * 7 + x1] +
                  w10 * pa[y1 * 7 + x0] + w11 * pa[y1 * 7 + x1];
    const float* pn = na_b + (h * NA + a) * 49;
    float up_na = w00 * pn[y0 * 7 + x0] + w01 * pn[y0 * 7 + x1] +
                  w10 * pn[y1 * 7 + x0] + w11 * pn[y1 * 7 + x1];
    float pb = up_an + ah_b[(h * NA + a) * 56 + y] + aw_b[(h * NA + a) * 56 + x];
    pos_bias[((size_t)(h * NAP + a)) * NTOK + n] = pb;
    float ab = up_na + ha_b[(h * 56 + y) * NA + a] + wa_b[(h * 56 + x) * NA + a];
    agent_bias[((size_t)(h * NAP + a)) * NTOK + n] = ab;
  }
  for (int a = NA; a < NAP; ++a)
    pos_bias[((size_t)(h * NAP + a)) * NTOK + n] = 0.f;
}

// ---------------- f16 MFMA GEMM: C[M,N] = A[M,256] * Bw[N,256]^T ----------------
// BM=BN=128, BK=32, 256 threads (4 waves, 2x2 of 64x64).
// XCD-clustered 1D grid: wrk = (bid%8)*(nwg/8) + bid/8, n-fastest -> one XCD owns an A-panel.
// Single-barrier double-buffered pipeline: loads for k+1 issue before MFMA on k (T14).
template <bool PROJ, bool AF32>
__global__ __launch_bounds__(256) void k_gemm(const void* __restrict__ Av, const f16* __restrict__ Bw,
                                              f16* __restrict__ Cf16, float* __restrict__ Cf32,
                                              const float* __restrict__ bias, int N) {
  __shared__ __align__(16) char lds[2][20480];   // per buf: A 10240 | B 10240 (rows stride 80)
  int per = gridDim.x >> 3;
  int wrk = (blockIdx.x & 7) * per + (blockIdx.x >> 3);
  int nNT = N >> 7;
  int mt = wrk / nNT, nt = wrk - mt * nNT;
  int m0 = mt * 128, n0 = nt * 128;
  int tid = threadIdx.x, w = tid >> 6, l = tid & 63, lr = l & 15, lg = l >> 4;
  int wm = w >> 1, wn = w & 1;
  f32x4 acc[4][4] = {};
  const char* Bbase = (const char*)Bw + (size_t)n0 * 512;
  const float* Af32 = (const float*)Av;
  const char* Ab16 = (const char*)Av + (size_t)m0 * 512;
  int c0 = tid, c1 = 256 + tid;
  int r0 = c0 >> 2, q0 = c0 & 3, r1 = c1 >> 2, q1 = c1 & 3;

  float4 a0v0, a0v1, a1v0, a1v1;
  half8 ah0, ah1, b0, b1;

  auto LOAD = [&](int k0) {
    if (AF32) {
      const float* s0 = Af32 + (size_t)(m0 + r0) * 256 + k0 + q0 * 8;
      const float* s1 = Af32 + (size_t)(m0 + r1) * 256 + k0 + q1 * 8;
      a0v0 = *(const float4*)s0; a0v1 = *(const float4*)(s0 + 4);
      a1v0 = *(const float4*)s1; a1v1 = *(const float4*)(s1 + 4);
    } else {
      ah0 = *(const half8*)(Ab16 + (size_t)r0 * 512 + k0 * 2 + q0 * 16);
      ah1 = *(const half8*)(Ab16 + (size_t)r1 * 512 + k0 * 2 + q1 * 16);
    }
    b0 = *(const half8*)(Bbase + (size_t)r0 * 512 + k0 * 2 + q0 * 16);
    b1 = *(const half8*)(Bbase + (size_t)r1 * 512 + k0 * 2 + q1 * 16);
  };
  auto STORE = [&](char* buf) {
    half8 ha0, ha1;
    if (AF32) {
      union { half8 h; fp16x2 h2[4]; } u0, u1;
      u0.h2[0] = __builtin_amdgcn_cvt_pkrtz(a0v0.x, a0v0.y);
      u0.h2[1] = __builtin_amdgcn_cvt_pkrtz(a0v0.z, a0v0.w);
      u0.h2[2] = __builtin_amdgcn_cvt_pkrtz(a0v1.x, a0v1.y);
      u0.h2[3] = __builtin_amdgcn_cvt_pkrtz(a0v1.z, a0v1.w);
      u1.h2[0] = __builtin_amdgcn_cvt_pkrtz(a1v0.x, a1v0.y);
      u1.h2[1] = __builtin_amdgcn_cvt_pkrtz(a1v0.z, a1v0.w);
      u1.h2[2] = __builtin_amdgcn_cvt_pkrtz(a1v1.x, a1v1.y);
      u1.h2[3] = __builtin_amdgcn_cvt_pkrtz(a1v1.z, a1v1.w);
      ha0 = u0.h; ha1 = u1.h;
    } else {
      ha0 = ah0; ha1 = ah1;
    }
    *(half8*)(buf + r0 * 80 + q0 * 16) = ha0;
    *(half8*)(buf + r1 * 80 + q1 * 16) = ha1;
    *(half8*)(buf + 10240 + r0 * 80 + q0 * 16) = b0;
    *(half8*)(buf + 10240 + r1 * 80 + q1 * 16) = b1;
  };
  auto COMPUTE = [&](const char* buf) {
    half8 af[4], bf[4];
#pragma unroll
    for (int mt4 = 0; mt4 < 4; ++mt4) {
      int row = wm * 64 + mt4 * 16 + lr;
      af[mt4] = *(const half8*)(buf + row * 80 + lg * 16);
    }
#pragma unroll
    for (int nt4 = 0; nt4 < 4; ++nt4) {
      int row = wn * 64 + nt4 * 16 + lr;
      bf[nt4] = *(const half8*)(buf + 10240 + row * 80 + lg * 16);
    }
#pragma unroll
    for (int mt4 = 0; mt4 < 4; ++mt4)
#pragma unroll
      for (int nt4 = 0; nt4 < 4; ++nt4)
        acc[mt4][nt4] = mfma16(af[mt4], bf[nt4], acc[mt4][nt4]);
  };

  LOAD(0);
  STORE(lds[0]);
  __syncthreads();
  int cur = 0;
  for (int k0 = 32; k0 < 256; k0 += 32) {
    LOAD(k0);               // global loads in flight...
    COMPUTE(lds[cur]);      // ...hide under MFMA
    STORE(lds[cur ^ 1]);    // vmcnt wait happens here
    __syncthreads();
    cur ^= 1;
  }
  COMPUTE(lds[cur]);

#pragma unroll
  for (int mt4 = 0; mt4 < 4; ++mt4)
#pragma unroll
    for (int nt4 = 0; nt4 < 4; ++nt4)
#pragma unroll
      for (int r = 0; r < 4; ++r) {
        int m = m0 + wm * 64 + mt4 * 16 + lg * 4 + r;
        int n = n0 + wn * 64 + nt4 * 16 + lr;
        if (PROJ)
          Cf32[(size_t)m * N + n] = acc[mt4][nt4][r] + bias[n];
        else
          Cf16[(size_t)m * N + n] = (f16)acc[mt4][nt4][r];
      }
}

// ---------------- agent pooling (scaled) + token means ----------------
__global__ __launch_bounds__(256) void k_pool_tw(const f16* qkv, f16* agent, float* tw) {
  int bh = blockIdx.x, b = bh >> 3, h = bh & 7;
  int tid = threadIdx.x;
  for (int s = tid; s < NAP * 32; s += 256) {
    int a = s >> 5, d = s & 31;
    float val = 0.f;
    if (a < NA) {
      int dh = a / 7, dwi = a - dh * 7;
      float sum = 0.f;
      for (int i = 0; i < 8; ++i)
        for (int j = 0; j < 8; ++j) {
          int n = (dh * 8 + i) * 56 + dwi * 8 + j;
          sum += (float)qkv[((size_t)(b * NTOK + n)) * QLD + h * 32 + d];
        }
      val = sum * (SCALE / 64.f);
    }
    agent[(size_t)bh * NAP * 32 + s] = (f16)val;
  }
  for (int n = tid; n < NTOK; n += 256) {
    const half8* qp = (const half8*)(qkv + ((size_t)(b * NTOK + n)) * QLD + h * 32);
    float sum = 0.f;
#pragma unroll
    for (int j = 0; j < 4; ++j) {
      half8 v = qp[j];
#pragma unroll
      for (int e = 0; e < 8; ++e) sum += (float)v[e];
    }
    tw[(size_t)bh * NTOK + n] = sum * (1.f / 32.f);
  }
}

// ---------------- exact top-k (desc value, asc index) via bitonic sort ----------------
__global__ __launch_bounds__(1024) void k_topk(const float* tw, int* topidx) {
  __shared__ unsigned long long keys[4096];
  int bh = blockIdx.x, tid = threadIdx.x;
  const float* p = tw + (size_t)bh * NTOK;
  for (int s = tid; s < 4096; s += 1024) {
    float v = (s < NTOK) ? p[s] : -1e30f;
    unsigned ub = __float_as_uint(v);
    ub = (ub & 0x80000000u) ? ~ub : (ub | 0x80000000u);
    unsigned low = (s < NTOK) ? ~(unsigned)s : 0u;
    keys[s] = ((unsigned long long)ub << 32) | low;
  }
  for (int k = 2; k <= 4096; k <<= 1)
    for (int j = k >> 1; j > 0; j >>= 1) {
      __syncthreads();
      for (int i = tid; i < 4096; i += 1024) {
        int ixj = i ^ j;
        if (ixj > i) {
          unsigned long long a = keys[i], c = keys[ixj];
          bool lt = a < c;
          bool descRegion = ((i & k) == 0);
          if (lt == descRegion) { keys[i] = c; keys[ixj] = a; }
        }
      }
    }
  __syncthreads();
  for (int t = tid; t < TTOP; t += 1024)
    topidx[(size_t)bh * TTOP + t] = (int)(~(unsigned)keys[t]);
}

// ---------------- v transpose: vt[bh][d=32][n=3136] ----------------
__global__ __launch_bounds__(256) void k_vt(const f16* qkv, f16* vt) {
  __shared__ f16 t[64][33];
  int bh = blockIdx.y, b = bh >> 3, h = bh & 7;
  int n0 = blockIdx.x * 64;
  int tid = threadIdx.x;
  for (int s = tid; s < 64 * 32; s += 256) {
    int nl = s >> 5, d = s & 31;
    t[nl][d] = qkv[((size_t)(b * NTOK + n0 + nl)) * QLD + 512 + h * 32 + d];
  }
  __syncthreads();
  for (int s = tid; s < 64 * 32; s += 256) {
    int d = s >> 6, nl = s & 63;
    vt[((size_t)(bh * 32 + d)) * NTOK + n0 + nl] = t[nl][d];
  }
}

// ---------------- fused agent attention: softmax_n(agent_s . k^T + bias) @ v ----------------
__global__ __launch_bounds__(256) void k_flash(const f16* qkv, const f16* agent, const f16* vt,
                                               const float* pos_bias, float* agent_v) {
  __shared__ __align__(16) f16 pbuf[4][64][40];
  __shared__ float ored[64][33];
  __shared__ float rssum[64];
  int bh = blockIdx.x, b = bh >> 3, h = bh & 7;
  int tid = threadIdx.x, w = tid >> 6, l = tid & 63, lr = l & 15, lg = l >> 4;
  half8 afrag[4];
#pragma unroll
  for (int mt = 0; mt < 4; ++mt)
    afrag[mt] = *(const half8*)(agent + ((size_t)bh * 64 + mt * 16 + lr) * 32 + lg * 8);
  f32x4 o[4][2] = {};
  float rs[4][4] = {};
  const f16* kbase = qkv + (size_t)b * NTOK * QLD + 256 + h * 32;
  const f16* vtb = vt + (size_t)bh * 32 * NTOK;
  const float* pbb = pos_bias + (size_t)h * NAP * NTOK;
  f32x4 zero = {};
  for (int n0 = w * 32; n0 < NTOK; n0 += 128) {
#pragma unroll
    for (int t2 = 0; t2 < 2; ++t2) {
      int nc = n0 + t2 * 16;
      half8 kf = *(const half8*)(kbase + (size_t)(nc + lr) * QLD + lg * 8);
#pragma unroll
      for (int mt = 0; mt < 4; ++mt) {
        f32x4 s = mfma16(afrag[mt], kf, zero);
#pragma unroll
        for (int r = 0; r < 4; ++r) {
          int a = mt * 16 + lg * 4 + r;
          float pv = __expf(s[r] + pbb[(size_t)a * NTOK + nc + lr]);
          rs[mt][r] += pv;
          pbuf[w][a][t2 * 16 + lr] = (f16)pv;
        }
      }
    }
    half8 pf[4];
#pragma unroll
    for (int mt = 0; mt < 4; ++mt)
      pf[mt] = *(const half8*)(&pbuf[w][mt * 16 + lr][lg * 8]);
#pragma unroll
    for (int dt = 0; dt < 2; ++dt) {
      half8 vf = *(const half8*)(vtb + (size_t)(dt * 16 + lr) * NTOK + n0 + lg * 8);
#pragma unroll
      for (int mt = 0; mt < 4; ++mt)
        o[mt][dt] = mfma16(pf[mt], vf, o[mt][dt]);
    }
  }
#pragma unroll
  for (int mt = 0; mt < 4; ++mt)
#pragma unroll
    for (int r = 0; r < 4; ++r) {
      float v = rs[mt][r];
      for (int off = 1; off < 16; off <<= 1) v += __shfl_xor(v, off, 64);
      rs[mt][r] = v;
    }
  for (int s = tid; s < 64 * 33; s += 256) ((float*)ored)[s] = 0.f;
  if (tid < 64) rssum[tid] = 0.f;
  __syncthreads();
  for (int ww = 0; ww < 4; ++ww) {
    if (w == ww) {
      if (lr == 0)
#pragma unroll
        for (int mt = 0; mt < 4; ++mt)
#pragma unroll
          for (int r = 0; r < 4; ++r) rssum[mt * 16 + lg * 4 + r] += rs[mt][r];
#pragma unroll
      for (int mt = 0; mt < 4; ++mt)
#pragma unroll
        for (int dt = 0; dt < 2; ++dt)
#pragma unroll
          for (int r = 0; r < 4; ++r)
            ored[mt * 16 + lg * 4 + r][dt * 16 + lr] += o[mt][dt][r];
    }
    __syncthreads();
  }
  for (int s = tid; s < NA * 32; s += 256) {
    int a = s >> 5, d = s & 31;
    agent_v[(size_t)bh * NA * 32 + s] = ored[a][d] / rssum[a];
  }
}

// ---------------- k_psm: q2 gather-MFMA -> resize -> exp -> P (fragment layout) + ssum ----------------
__global__ __launch_bounds__(256) void k_psm(const f16* qkv, const f16* agent, const int* topidx,
                                             const float* agent_bias, f16* P, float* ssumg) {
  __shared__ __align__(16) f16 q2buf[144][88];
  int chunk = blockIdx.x, bh = blockIdx.y, b = bh >> 3, h = bh & 7;
  int tid = threadIdx.x, w = tid >> 6, l = tid & 63, lr = l & 15, lg = l >> 4;
  half8 bfrag[4];
#pragma unroll
  for (int nt = 0; nt < 4; ++nt)
    bfrag[nt] = *(const half8*)(agent + ((size_t)bh * 64 + nt * 16 + lr) * 32 + lg * 8);
  int jbase = chunk * 128 - 8;
  f32x4 zero = {};
  for (int mt = w; mt < 9; mt += 4) {
    int j = jbase + mt * 16 + lr;
    int jc = min(max(j, 0), TTOP - 1);
    int tok = topidx[(size_t)bh * TTOP + jc];
    half8 qf = *(const half8*)(qkv + ((size_t)(b * NTOK + tok)) * QLD + h * 32 + lg * 8);
#pragma unroll
    for (int nt = 0; nt < 4; ++nt) {
      f32x4 s = mfma16(qf, bfrag[nt], zero);
#pragma unroll
      for (int r = 0; r < 4; ++r)
        q2buf[mt * 16 + lg * 4 + r][nt * 16 + lr] = (f16)s[r];
    }
  }
  __syncthreads();
  int g = chunk * 256 + tid;
  if (g >= NTOK) return;
  int hi = g >> 1;
  int jA, jB; float wAq, wBq;
  if (g & 1) { jA = hi; jB = hi + 1; wAq = 0.75f; wBq = 0.25f; }
  else       { jA = hi - 1; jB = hi; wAq = 0.25f; wBq = 0.75f; }
  jA = min(max(jA, 0), TTOP - 1);
  jB = min(max(jB, 0), TTOP - 1);
  int lA = jA - jbase, lB = jB - jbase;
  const float* ab = agent_bias + (size_t)h * NAP * NTOK + g;
  f16* Pb = P + (size_t)bh * PBH;
  int tile = g >> 4, lrr = g & 15;
  float ssum = 0.f;
#pragma unroll
  for (int c = 0; c < 7; ++c) {
    half8 a8 = *(const half8*)(&q2buf[lA][c * 8]);
    half8 b8 = *(const half8*)(&q2buf[lB][c * 8]);
    half8 o;
#pragma unroll
    for (int e = 0; e < 8; ++e) {
      int a = c * 8 + e;
      float pv = 0.f;
      if (a < NA) {
        float v = wAq * (float)a8[e] + wBq * (float)b8[e] + ab[(size_t)a * NTOK];
        pv = __expf(v);
        ssum += pv;
      }
      o[e] = (f16)pv;
    }
    *(half8*)(Pb + ((size_t)(tile * 8 + c) * 16 + lrr) * 8) = o;
  }
  half8 z = {};
  *(half8*)(Pb + ((size_t)(tile * 8 + 7) * 16 + lrr) * 8) = z;
  ssumg[(size_t)bh * NTOK + g] = ssum;
}

// ---------------- k_out: C = (P @ avT)/ssum  + dwconv, write pre ----------------
__global__ __launch_bounds__(256) void k_out(const f16* P, const float* ssumg, const float* agent_v,
                                             const f16* qkv, const float* dwc_w, const float* dwc_b,
                                             f16* pre) {
  __shared__ __align__(16) f16 avT[32][72];
  __shared__ __align__(16) f16 ctile[256][40];
  __shared__ float wconv[9][32];
  __shared__ float bconv[32];
  int chunk = blockIdx.x, bh = blockIdx.y, b = bh >> 3, h = bh & 7;
  int tid = threadIdx.x, w = tid >> 6, l = tid & 63, lr = l & 15, lg = l >> 4;
  for (int s = tid; s < 32 * 64; s += 256) {
    int d = s >> 6, a = s & 63;
    avT[d][a] = (a < NA) ? (f16)agent_v[((size_t)bh * NA + a) * 32 + d] : (f16)0.f;
  }
  for (int s = tid; s < 32 * 9; s += 256) {
    int d = s / 9, t = s - d * 9;
    wconv[t][d] = dwc_w[(size_t)(h * 32 + d) * 9 + t];
  }
  if (tid < 32) bconv[tid] = dwc_b[h * 32 + tid];
  __syncthreads();
  half8 bf[2][2];
#pragma unroll
  for (int nt = 0; nt < 2; ++nt)
#pragma unroll
    for (int ks = 0; ks < 2; ++ks)
      bf[nt][ks] = *(const half8*)(&avT[0][0] + (size_t)(nt * 16 + lr) * 72 + ks * 32 + lg * 8);
  const f16* Pb = P + (size_t)bh * PBH;
#pragma unroll
  for (int mt = 0; mt < 4; ++mt) {
    int tile = chunk * 16 + w * 4 + mt;
    if (tile >= NTILES) continue;
    const f16* Pt = Pb + (size_t)tile * 1024;
    half8 a0 = *(const half8*)(Pt + ((size_t)(0 + lg) * 16 + lr) * 8);
    half8 a1 = *(const half8*)(Pt + ((size_t)(4 + lg) * 16 + lr) * 8);
    f32x4 acc0 = {}, acc1 = {};
    acc0 = mfma16(a0, bf[0][0], acc0);
    acc0 = mfma16(a1, bf[0][1], acc0);
    acc1 = mfma16(a0, bf[1][0], acc1);
    acc1 = mfma16(a1, bf[1][1], acc1);
    int ltrow = (w * 4 + mt) * 16 + lg * 4;
#pragma unroll
    for (int r = 0; r < 4; ++r) {
      float ss = ssumg[(size_t)bh * NTOK + tile * 16 + lg * 4 + r];
      float inv = 1.f / ss;
      ctile[ltrow + r][lr] = (f16)(acc0[r] * inv);
      ctile[ltrow + r][16 + lr] = (f16)(acc1[r] * inv);
    }
  }
  __syncthreads();
  int g = chunk * 256 + tid;
  if (g >= NTOK) return;
  float accd[32];
#pragma unroll
  for (int c = 0; c < 4; ++c) {
    half8 cv = *(const half8*)(&ctile[tid][c * 8]);
#pragma unroll
    for (int e = 0; e < 8; ++e) accd[c * 8 + e] = (float)cv[e] + bconv[c * 8 + e];
  }
  int y = g / 56, x = g - y * 56;
  const f16* vbase = qkv + (size_t)b * NTOK * QLD + 512 + h * 32;
#pragma unroll
  for (int ky = 0; ky < 3; ++ky) {
    int yy = y + ky - 1;
    if (yy < 0 || yy >= 56) continue;
#pragma unroll
    for (int kx = 0; kx < 3; ++kx) {
      int xx = x + kx - 1;
      if (xx < 0 || xx >= 56) continue;
      int t = ky * 3 + kx;
      const f16* vp = vbase + (size_t)(yy * 56 + xx) * QLD;
#pragma unroll
      for (int c = 0; c < 4; ++c) {
        half8 vv = *(const half8*)(vp + c * 8);
#pragma unroll
        for (int e = 0; e < 8; ++e) accd[c * 8 + e] += wconv[t][c * 8 + e] * (float)vv[e];
      }
    }
  }
  f16* op = pre + ((size_t)(b * NTOK + g)) * 256 + h * 32;
#pragma unroll
  for (int c = 0; c < 4; ++c) {
    half8 o;
#pragma unroll
    for (int e = 0; e < 8; ++e) o[e] = (f16)accd[c * 8 + e];
    *(half8*)(op + c * 8) = o;
  }
}

extern "C" void kernel_launch(void* const* d_in, const int* in_sizes, int n_in,
                              void* d_out, int out_size, void* d_ws, size_t ws_size,
                              hipStream_t stream) {
  const float* x     = (const float*)d_in[0];
  const float* Wq    = (const float*)d_in[3];
  const float* Wkv   = (const float*)d_in[4];
  const float* Wproj = (const float*)d_in[5];
  const float* bproj = (const float*)d_in[6];
  const float* dwc_w = (const float*)d_in[7];
  const float* dwc_b = (const float*)d_in[8];
  const float* an_b  = (const float*)d_in[9];
  const float* na_b  = (const float*)d_in[10];
  const float* ah_b  = (const float*)d_in[11];
  const float* aw_b  = (const float*)d_in[12];
  const float* ha_b  = (const float*)d_in[13];
  const float* wa_b  = (const float*)d_in[14];

  char* ws = (char*)d_ws;
  size_t off = 0;
  auto alloc = [&](size_t bytes) {
    void* p = ws + off;
    off = (off + bytes + 255) & ~(size_t)255;
    return p;
  };
  f16* wqkv    = (f16*)alloc((size_t)768 * 256 * 2);
  f16* wproj   = (f16*)alloc((size_t)256 * 256 * 2);
  f16* qkv     = (f16*)alloc((size_t)50176 * 768 * 2);
  float* posb  = (float*)alloc((size_t)8 * NAP * NTOK * 4);
  float* agb   = (float*)alloc((size_t)8 * NAP * NTOK * 4);
  f16* agent   = (f16*)alloc((size_t)128 * NAP * 32 * 2);
  float* tw    = (float*)alloc((size_t)128 * NTOK * 4);
  int* topidx  = (int*)alloc((size_t)128 * TTOP * 4);
  f16* vt      = (f16*)alloc((size_t)128 * 32 * NTOK * 2);
  float* agv   = (float*)alloc((size_t)128 * NA * 32 * 4);
  f16* pre     = (f16*)alloc((size_t)50176 * 256 * 2);
  f16* P       = (f16*)alloc((size_t)128 * PBH * 2);
  float* ssumg = tw;  // tw dead after k_topk

  k_prep_w<<<1024, 256, 0, stream>>>(Wq, Wkv, Wproj, wqkv, wproj);
  k_bias<<<dim3(13, 8), 256, 0, stream>>>(an_b, na_b, ah_b, aw_b, ha_b, wa_b, posb, agb);
  k_gemm<false, true><<<2352, 256, 0, stream>>>(x, wqkv, qkv, nullptr, nullptr, 768);
  k_pool_tw<<<128, 256, 0, stream>>>(qkv, agent, tw);
  k_topk<<<128, 1024, 0, stream>>>(tw, topidx);
  k_vt<<<dim3(49, 128), 256, 0, stream>>>(qkv, vt);
  k_flash<<<128, 256, 0, stream>>>(qkv, agent, vt, posb, agv);
  k_psm<<<dim3(13, 128), 256, 0, stream>>>(qkv, agent, topidx, agb, P, ssumg);
  k_out<<<dim3(13, 128), 256, 0, stream>>>(P, ssumg, agv, qkv, dwc_w, dwc_b, pre);
  k_gemm<true, false><<<784, 256, 0, stream>>>(pre, wproj, nullptr, (float*)d_out, bproj, 256);
}

// Round 7
// 330.162 us; speedup vs baseline: 1.4959x; 1.0517x over previous
//
#include <hip/hip_runtime.h>
#include <stdint.h>

typedef _Float16 f16;
typedef _Float16 half8 __attribute__((ext_vector_type(8)));
typedef float f32x4 __attribute__((ext_vector_type(4)));

#define NBATCH 16
#define NTOK 3136
#define NH 8
#define NA 49
#define NAP 64
#define TTOP 1568
#define QLD 768
#define NTILES 196          // NTOK/16
#define PBH 200704          // NTILES*8*16*8 f16 elements per bh
#define SCALE 0.17677669529663687f

__device__ __forceinline__ f32x4 mfma16(half8 a, half8 b, f32x4 c) {
  return __builtin_amdgcn_mfma_f32_16x16x32_f16(a, b, c, 0, 0, 0);
}

// global -> LDS direct DMA, 16B per lane. LDS dest is wave-uniform base + lane*16.
__device__ __forceinline__ void gload16(const void* g, void* l) {
  __builtin_amdgcn_global_load_lds(
      (const __attribute__((address_space(1))) void*)g,
      (__attribute__((address_space(3))) void*)l, 16, 0, 0);
}

// ---------------- weight conversion ----------------
__global__ __launch_bounds__(256) void k_prep_w(const float* Wq, const float* Wkv, const float* Wproj,
                                                f16* wqkv, f16* wproj) {
  int total1 = 768 * 256;
  int total = total1 + 256 * 256;
  for (int i = blockIdx.x * 256 + threadIdx.x; i < total; i += gridDim.x * 256) {
    if (i < total1) {
      int j = i >> 8, k = i & 255;
      float v = (j < 256) ? Wq[j * 256 + k] : Wkv[(j - 256) * 256 + k];
      wqkv[i] = (f16)v;
    } else {
      int i2 = i - total1;
      wproj[i2] = (f16)Wproj[i2];
    }
  }
}

// ---------------- x f32 -> f16 ----------------
__global__ __launch_bounds__(256) void k_cvt_x(const float* x, f16* xh, long total) {
  long i = (long)blockIdx.x * blockDim.x + threadIdx.x;
  long stride = (long)gridDim.x * blockDim.x;
  for (long e = i * 8; e < total; e += stride * 8) {
    float4 v0 = *(const float4*)(x + e);
    float4 v1 = *(const float4*)(x + e + 4);
    half8 o = {(f16)v0.x, (f16)v0.y, (f16)v0.z, (f16)v0.w,
               (f16)v1.x, (f16)v1.y, (f16)v1.z, (f16)v1.w};
    *(half8*)(xh + e) = o;
  }
}

// ---------------- bias precompute ----------------
__global__ __launch_bounds__(256) void k_bias(const float* an_b, const float* na_b,
                                              const float* ah_b, const float* aw_b,
                                              const float* ha_b, const float* wa_b,
                                              float* pos_bias, float* agent_bias) {
  int n = blockIdx.x * 256 + threadIdx.x;
  int h = blockIdx.y;
  if (n >= NTOK) return;
  int y = n / 56, x = n - y * 56;
  float py = (y + 0.5f) * 0.125f - 0.5f;
  float px = (x + 0.5f) * 0.125f - 0.5f;
  int iy0 = (int)floorf(py); float fy = py - (float)iy0;
  int ix0 = (int)floorf(px); float fx = px - (float)ix0;
  int y0 = max(iy0, 0), y1 = min(iy0 + 1, 6);
  int x0 = max(ix0, 0), x1 = min(ix0 + 1, 6);
  float w00 = (1.f - fy) * (1.f - fx), w01 = (1.f - fy) * fx;
  float w10 = fy * (1.f - fx), w11 = fy * fx;
  for (int a = 0; a < NA; ++a) {
    const float* pa = an_b + (h * NA + a) * 49;
    float up_an = w00 * pa[y0 * 7 + x0] + w01 * pa[y0 * 7 + x1] +
                  w10 * pa[y1 * 7 + x0] + w11 * pa[y1 * 7 + x1];
    const float* pn = na_b + (h * NA + a) * 49;
    float up_na = w00 * pn[y0 * 7 + x0] + w01 * pn[y0 * 7 + x1] +
                  w10 * pn[y1 * 7 + x0] + w11 * pn[y1 * 7 + x1];
    float pb = up_an + ah_b[(h * NA + a) * 56 + y] + aw_b[(h * NA + a) * 56 + x];
    pos_bias[((size_t)(h * NAP + a)) * NTOK + n] = pb;
    float ab = up_na + ha_b[(h * 56 + y) * NA + a] + wa_b[(h * 56 + x) * NA + a];
    agent_bias[((size_t)(h * NAP + a)) * NTOK + n] = ab;
  }
  for (int a = NA; a < NAP; ++a)
    pos_bias[((size_t)(h * NAP + a)) * NTOK + n] = 0.f;
}

// ---------------- f16 MFMA GEMM (m97 structure): C[M,N] = A[M,256] * Bw[N,256]^T ----------------
// BM=BN=128, BK=32, 256 threads (4 waves, 2x2 of 64x64).
// global_load_lds width-16 staging into a single linear LDS buffer; 2 barriers per K-step;
// latency hidden by inter-block TLP (16KB LDS -> ~4 blocks/CU).
// XCD-clustered 1D grid: wrk = (bid%8)*(nwg/8) + bid/8, n-fastest.
template <bool PROJ>
__global__ __launch_bounds__(256) void k_gemm(const f16* __restrict__ A, const f16* __restrict__ Bw,
                                              f16* __restrict__ Cf16, float* __restrict__ Cf32,
                                              const float* __restrict__ bias, int N) {
  __shared__ __align__(16) char lds[16384];   // A 8KB | B 8KB, rows linear 64B
  int per = gridDim.x >> 3;
  int wrk = (blockIdx.x & 7) * per + (blockIdx.x >> 3);
  int nNT = N >> 7;
  int mt = wrk / nNT, nt = wrk - mt * nNT;
  int m0 = mt * 128, n0 = nt * 128;
  int tid = threadIdx.x, w = tid >> 6, l = tid & 63, lr = l & 15, lg = l >> 4;
  int wm = w >> 1, wn = w & 1;
  f32x4 acc[4][4] = {};
  const char* Ab = (const char*)A + (size_t)m0 * 512;
  const char* Bb = (const char*)Bw + (size_t)n0 * 512;
  // wave w stages 1KB chunks {2w, 2w+1} of both A and B tiles.
  // chunk c covers rows 16c..16c+15; lane l -> row 16c + (l>>2), byte (l&3)*16 in row.
  int rowA0 = 32 * w + (l >> 2);
  int rowA1 = rowA0 + 16;
  int koff = (l & 3) * 16;
  char* ldsA0 = lds + (2 * w) * 1024;          // wave-uniform
  char* ldsA1 = lds + (2 * w + 1) * 1024;
  char* ldsB0 = lds + 8192 + (2 * w) * 1024;
  char* ldsB1 = lds + 8192 + (2 * w + 1) * 1024;

  for (int k0 = 0; k0 < 256; k0 += 32) {
    gload16(Ab + (size_t)rowA0 * 512 + k0 * 2 + koff, ldsA0);
    gload16(Ab + (size_t)rowA1 * 512 + k0 * 2 + koff, ldsA1);
    gload16(Bb + (size_t)rowA0 * 512 + k0 * 2 + koff, ldsB0);
    gload16(Bb + (size_t)rowA1 * 512 + k0 * 2 + koff, ldsB1);
    __syncthreads();   // drains vmcnt -> LDS tile complete
    half8 af[4], bf[4];
#pragma unroll
    for (int m4 = 0; m4 < 4; ++m4) {
      int row = wm * 64 + m4 * 16 + lr;
      af[m4] = *(const half8*)(lds + row * 64 + lg * 16);
    }
#pragma unroll
    for (int n4 = 0; n4 < 4; ++n4) {
      int row = wn * 64 + n4 * 16 + lr;
      bf[n4] = *(const half8*)(lds + 8192 + row * 64 + lg * 16);
    }
#pragma unroll
    for (int m4 = 0; m4 < 4; ++m4)
#pragma unroll
      for (int n4 = 0; n4 < 4; ++n4)
        acc[m4][n4] = mfma16(af[m4], bf[n4], acc[m4][n4]);
    __syncthreads();   // before overwriting LDS
  }

#pragma unroll
  for (int m4 = 0; m4 < 4; ++m4)
#pragma unroll
    for (int n4 = 0; n4 < 4; ++n4)
#pragma unroll
      for (int r = 0; r < 4; ++r) {
        int m = m0 + wm * 64 + m4 * 16 + lg * 4 + r;
        int n = n0 + wn * 64 + n4 * 16 + lr;
        if (PROJ)
          Cf32[(size_t)m * N + n] = acc[m4][n4][r] + bias[n];
        else
          Cf16[(size_t)m * N + n] = (f16)acc[m4][n4][r];
      }
}

// ---------------- agent pooling (scaled) + token means ----------------
__global__ __launch_bounds__(256) void k_pool_tw(const f16* qkv, f16* agent, float* tw) {
  int bh = blockIdx.x, b = bh >> 3, h = bh & 7;
  int tid = threadIdx.x;
  for (int s = tid; s < NAP * 32; s += 256) {
    int a = s >> 5, d = s & 31;
    float val = 0.f;
    if (a < NA) {
      int dh = a / 7, dwi = a - dh * 7;
      float sum = 0.f;
      for (int i = 0; i < 8; ++i)
        for (int j = 0; j < 8; ++j) {
          int n = (dh * 8 + i) * 56 + dwi * 8 + j;
          sum += (float)qkv[((size_t)(b * NTOK + n)) * QLD + h * 32 + d];
        }
      val = sum * (SCALE / 64.f);
    }
    agent[(size_t)bh * NAP * 32 + s] = (f16)val;
  }
  for (int n = tid; n < NTOK; n += 256) {
    const half8* qp = (const half8*)(qkv + ((size_t)(b * NTOK + n)) * QLD + h * 32);
    float sum = 0.f;
#pragma unroll
    for (int j = 0; j < 4; ++j) {
      half8 v = qp[j];
#pragma unroll
      for (int e = 0; e < 8; ++e) sum += (float)v[e];
    }
    tw[(size_t)bh * NTOK + n] = sum * (1.f / 32.f);
  }
}

// ---------------- exact top-k (desc value, asc index) via bitonic sort ----------------
__global__ __launch_bounds__(1024) void k_topk(const float* tw, int* topidx) {
  __shared__ unsigned long long keys[4096];
  int bh = blockIdx.x, tid = threadIdx.x;
  const float* p = tw + (size_t)bh * NTOK;
  for (int s = tid; s < 4096; s += 1024) {
    float v = (s < NTOK) ? p[s] : -1e30f;
    unsigned ub = __float_as_uint(v);
    ub = (ub & 0x80000000u) ? ~ub : (ub | 0x80000000u);
    unsigned low = (s < NTOK) ? ~(unsigned)s : 0u;
    keys[s] = ((unsigned long long)ub << 32) | low;
  }
  for (int k = 2; k <= 4096; k <<= 1)
    for (int j = k >> 1; j > 0; j >>= 1) {
      __syncthreads();
      for (int i = tid; i < 4096; i += 1024) {
        int ixj = i ^ j;
        if (ixj > i) {
          unsigned long long a = keys[i], c = keys[ixj];
          bool lt = a < c;
          bool descRegion = ((i & k) == 0);
          if (lt == descRegion) { keys[i] = c; keys[ixj] = a; }
        }
      }
    }
  __syncthreads();
  for (int t = tid; t < TTOP; t += 1024)
    topidx[(size_t)bh * TTOP + t] = (int)(~(unsigned)keys[t]);
}

// ---------------- v transpose: vt[bh][d=32][n=3136] ----------------
__global__ __launch_bounds__(256) void k_vt(const f16* qkv, f16* vt) {
  __shared__ f16 t[64][33];
  int bh = blockIdx.y, b = bh >> 3, h = bh & 7;
  int n0 = blockIdx.x * 64;
  int tid = threadIdx.x;
  for (int s = tid; s < 64 * 32; s += 256) {
    int nl = s >> 5, d = s & 31;
    t[nl][d] = qkv[((size_t)(b * NTOK + n0 + nl)) * QLD + 512 + h * 32 + d];
  }
  __syncthreads();
  for (int s = tid; s < 64 * 32; s += 256) {
    int d = s >> 6, nl = s & 63;
    vt[((size_t)(bh * 32 + d)) * NTOK + n0 + nl] = t[nl][d];
  }
}

// ---------------- fused agent attention: softmax_n(agent_s . k^T + bias) @ v ----------------
__global__ __launch_bounds__(256) void k_flash(const f16* qkv, const f16* agent, const f16* vt,
                                               const float* pos_bias, float* agent_v) {
  __shared__ __align__(16) f16 pbuf[4][64][40];
  __shared__ float ored[64][33];
  __shared__ float rssum[64];
  int bh = blockIdx.x, b = bh >> 3, h = bh & 7;
  int tid = threadIdx.x, w = tid >> 6, l = tid & 63, lr = l & 15, lg = l >> 4;
  half8 afrag[4];
#pragma unroll
  for (int mt = 0; mt < 4; ++mt)
    afrag[mt] = *(const half8*)(agent + ((size_t)bh * 64 + mt * 16 + lr) * 32 + lg * 8);
  f32x4 o[4][2] = {};
  float rs[4][4] = {};
  const f16* kbase = qkv + (size_t)b * NTOK * QLD + 256 + h * 32;
  const f16* vtb = vt + (size_t)bh * 32 * NTOK;
  const float* pbb = pos_bias + (size_t)h * NAP * NTOK;
  f32x4 zero = {};
  for (int n0 = w * 32; n0 < NTOK; n0 += 128) {
#pragma unroll
    for (int t2 = 0; t2 < 2; ++t2) {
      int nc = n0 + t2 * 16;
      half8 kf = *(const half8*)(kbase + (size_t)(nc + lr) * QLD + lg * 8);
#pragma unroll
      for (int mt = 0; mt < 4; ++mt) {
        f32x4 s = mfma16(afrag[mt], kf, zero);
#pragma unroll
        for (int r = 0; r < 4; ++r) {
          int a = mt * 16 + lg * 4 + r;
          float pv = __expf(s[r] + pbb[(size_t)a * NTOK + nc + lr]);
          rs[mt][r] += pv;
          pbuf[w][a][t2 * 16 + lr] = (f16)pv;
        }
      }
    }
    half8 pf[4];
#pragma unroll
    for (int mt = 0; mt < 4; ++mt)
      pf[mt] = *(const half8*)(&pbuf[w][mt * 16 + lr][lg * 8]);
#pragma unroll
    for (int dt = 0; dt < 2; ++dt) {
      half8 vf = *(const half8*)(vtb + (size_t)(dt * 16 + lr) * NTOK + n0 + lg * 8);
#pragma unroll
      for (int mt = 0; mt < 4; ++mt)
        o[mt][dt] = mfma16(pf[mt], vf, o[mt][dt]);
    }
  }
#pragma unroll
  for (int mt = 0; mt < 4; ++mt)
#pragma unroll
    for (int r = 0; r < 4; ++r) {
      float v = rs[mt][r];
      for (int off = 1; off < 16; off <<= 1) v += __shfl_xor(v, off, 64);
      rs[mt][r] = v;
    }
  for (int s = tid; s < 64 * 33; s += 256) ((float*)ored)[s] = 0.f;
  if (tid < 64) rssum[tid] = 0.f;
  __syncthreads();
  for (int ww = 0; ww < 4; ++ww) {
    if (w == ww) {
      if (lr == 0)
#pragma unroll
        for (int mt = 0; mt < 4; ++mt)
#pragma unroll
          for (int r = 0; r < 4; ++r) rssum[mt * 16 + lg * 4 + r] += rs[mt][r];
#pragma unroll
      for (int mt = 0; mt < 4; ++mt)
#pragma unroll
        for (int dt = 0; dt < 2; ++dt)
#pragma unroll
          for (int r = 0; r < 4; ++r)
            ored[mt * 16 + lg * 4 + r][dt * 16 + lr] += o[mt][dt][r];
    }
    __syncthreads();
  }
  for (int s = tid; s < NA * 32; s += 256) {
    int a = s >> 5, d = s & 31;
    agent_v[(size_t)bh * NA * 32 + s] = ored[a][d] / rssum[a];
  }
}

// ---------------- k_psm: q2 gather-MFMA -> resize -> exp -> P (fragment layout) + ssum ----------------
__global__ __launch_bounds__(256) void k_psm(const f16* qkv, const f16* agent, const int* topidx,
                                             const float* agent_bias, f16* P, float* ssumg) {
  __shared__ __align__(16) f16 q2buf[144][88];
  int chunk = blockIdx.x, bh = blockIdx.y, b = bh >> 3, h = bh & 7;
  int tid = threadIdx.x, w = tid >> 6, l = tid & 63, lr = l & 15, lg = l >> 4;
  half8 bfrag[4];
#pragma unroll
  for (int nt = 0; nt < 4; ++nt)
    bfrag[nt] = *(const half8*)(agent + ((size_t)bh * 64 + nt * 16 + lr) * 32 + lg * 8);
  int jbase = chunk * 128 - 8;
  f32x4 zero = {};
  for (int mt = w; mt < 9; mt += 4) {
    int j = jbase + mt * 16 + lr;
    int jc = min(max(j, 0), TTOP - 1);
    int tok = topidx[(size_t)bh * TTOP + jc];
    half8 qf = *(const half8*)(qkv + ((size_t)(b * NTOK + tok)) * QLD + h * 32 + lg * 8);
#pragma unroll
    for (int nt = 0; nt < 4; ++nt) {
      f32x4 s = mfma16(qf, bfrag[nt], zero);
#pragma unroll
      for (int r = 0; r < 4; ++r)
        q2buf[mt * 16 + lg * 4 + r][nt * 16 + lr] = (f16)s[r];
    }
  }
  __syncthreads();
  int g = chunk * 256 + tid;
  if (g >= NTOK) return;
  int hi = g >> 1;
  int jA, jB; float wAq, wBq;
  if (g & 1) { jA = hi; jB = hi + 1; wAq = 0.75f; wBq = 0.25f; }
  else       { jA = hi - 1; jB = hi; wAq = 0.25f; wBq = 0.75f; }
  jA = min(max(jA, 0), TTOP - 1);
  jB = min(max(jB, 0), TTOP - 1);
  int lA = jA - jbase, lB = jB - jbase;
  const float* ab = agent_bias + (size_t)h * NAP * NTOK + g;
  f16* Pb = P + (size_t)bh * PBH;
  int tile = g >> 4, lrr = g & 15;
  float ssum = 0.f;
#pragma unroll
  for (int c = 0; c < 7; ++c) {
    half8 a8 = *(const half8*)(&q2buf[lA][c * 8]);
    half8 b8 = *(const half8*)(&q2buf[lB][c * 8]);
    half8 o;
#pragma unroll
    for (int e = 0; e < 8; ++e) {
      int a = c * 8 + e;
      float pv = 0.f;
      if (a < NA) {
        float v = wAq * (float)a8[e] + wBq * (float)b8[e] + ab[(size_t)a * NTOK];
        pv = __expf(v);
        ssum += pv;
      }
      o[e] = (f16)pv;
    }
    *(half8*)(Pb + ((size_t)(tile * 8 + c) * 16 + lrr) * 8) = o;
  }
  half8 z = {};
  *(half8*)(Pb + ((size_t)(tile * 8 + 7) * 16 + lrr) * 8) = z;
  ssumg[(size_t)bh * NTOK + g] = ssum;
}

// ---------------- k_out: C = (P @ avT)/ssum  + dwconv, write pre ----------------
__global__ __launch_bounds__(256) void k_out(const f16* P, const float* ssumg, const float* agent_v,
                                             const f16* qkv, const float* dwc_w, const float* dwc_b,
                                             f16* pre) {
  __shared__ __align__(16) f16 avT[32][72];
  __shared__ __align__(16) f16 ctile[256][40];
  __shared__ float wconv[9][32];
  __shared__ float bconv[32];
  int chunk = blockIdx.x, bh = blockIdx.y, b = bh >> 3, h = bh & 7;
  int tid = threadIdx.x, w = tid >> 6, l = tid & 63, lr = l & 15, lg = l >> 4;
  for (int s = tid; s < 32 * 64; s += 256) {
    int d = s >> 6, a = s & 63;
    avT[d][a] = (a < NA) ? (f16)agent_v[((size_t)bh * NA + a) * 32 + d] : (f16)0.f;
  }
  for (int s = tid; s < 32 * 9; s += 256) {
    int d = s / 9, t = s - d * 9;
    wconv[t][d] = dwc_w[(size_t)(h * 32 + d) * 9 + t];
  }
  if (tid < 32) bconv[tid] = dwc_b[h * 32 + tid];
  __syncthreads();
  half8 bf[2][2];
#pragma unroll
  for (int nt = 0; nt < 2; ++nt)
#pragma unroll
    for (int ks = 0; ks < 2; ++ks)
      bf[nt][ks] = *(const half8*)(&avT[0][0] + (size_t)(nt * 16 + lr) * 72 + ks * 32 + lg * 8);
  const f16* Pb = P + (size_t)bh * PBH;
#pragma unroll
  for (int mt = 0; mt < 4; ++mt) {
    int tile = chunk * 16 + w * 4 + mt;
    if (tile >= NTILES) continue;
    const f16* Pt = Pb + (size_t)tile * 1024;
    half8 a0 = *(const half8*)(Pt + ((size_t)(0 + lg) * 16 + lr) * 8);
    half8 a1 = *(const half8*)(Pt + ((size_t)(4 + lg) * 16 + lr) * 8);
    f32x4 acc0 = {}, acc1 = {};
    acc0 = mfma16(a0, bf[0][0], acc0);
    acc0 = mfma16(a1, bf[0][1], acc0);
    acc1 = mfma16(a0, bf[1][0], acc1);
    acc1 = mfma16(a1, bf[1][1], acc1);
    int ltrow = (w * 4 + mt) * 16 + lg * 4;
#pragma unroll
    for (int r = 0; r < 4; ++r) {
      float ss = ssumg[(size_t)bh * NTOK + tile * 16 + lg * 4 + r];
      float inv = 1.f / ss;
      ctile[ltrow + r][lr] = (f16)(acc0[r] * inv);
      ctile[ltrow + r][16 + lr] = (f16)(acc1[r] * inv);
    }
  }
  __syncthreads();
  int g = chunk * 256 + tid;
  if (g >= NTOK) return;
  float accd[32];
#pragma unroll
  for (int c = 0; c < 4; ++c) {
    half8 cv = *(const half8*)(&ctile[tid][c * 8]);
#pragma unroll
    for (int e = 0; e < 8; ++e) accd[c * 8 + e] = (float)cv[e] + bconv[c * 8 + e];
  }
  int y = g / 56, x = g - y * 56;
  const f16* vbase = qkv + (size_t)b * NTOK * QLD + 512 + h * 32;
#pragma unroll
  for (int ky = 0; ky < 3; ++ky) {
    int yy = y + ky - 1;
    if (yy < 0 || yy >= 56) continue;
#pragma unroll
    for (int kx = 0; kx < 3; ++kx) {
      int xx = x + kx - 1;
      if (xx < 0 || xx >= 56) continue;
      int t = ky * 3 + kx;
      const f16* vp = vbase + (size_t)(yy * 56 + xx) * QLD;
#pragma unroll
      for (int c = 0; c < 4; ++c) {
        half8 vv = *(const half8*)(vp + c * 8);
#pragma unroll
        for (int e = 0; e < 8; ++e) accd[c * 8 + e] += wconv[t][c * 8 + e] * (float)vv[e];
      }
    }
  }
  f16* op = pre + ((size_t)(b * NTOK + g)) * 256 + h * 32;
#pragma unroll
  for (int c = 0; c < 4; ++c) {
    half8 o;
#pragma unroll
    for (int e = 0; e < 8; ++e) o[e] = (f16)accd[c * 8 + e];
    *(half8*)(op + c * 8) = o;
  }
}

extern "C" void kernel_launch(void* const* d_in, const int* in_sizes, int n_in,
                              void* d_out, int out_size, void* d_ws, size_t ws_size,
                              hipStream_t stream) {
  const float* x     = (const float*)d_in[0];
  const float* Wq    = (const float*)d_in[3];
  const float* Wkv   = (const float*)d_in[4];
  const float* Wproj = (const float*)d_in[5];
  const float* bproj = (const float*)d_in[6];
  const float* dwc_w = (const float*)d_in[7];
  const float* dwc_b = (const float*)d_in[8];
  const float* an_b  = (const float*)d_in[9];
  const float* na_b  = (const float*)d_in[10];
  const float* ah_b  = (const float*)d_in[11];
  const float* aw_b  = (const float*)d_in[12];
  const float* ha_b  = (const float*)d_in[13];
  const float* wa_b  = (const float*)d_in[14];

  char* ws = (char*)d_ws;
  size_t off = 0;
  auto alloc = [&](size_t bytes) {
    void* p = ws + off;
    off = (off + bytes + 255) & ~(size_t)255;
    return p;
  };
  f16* wqkv    = (f16*)alloc((size_t)768 * 256 * 2);
  f16* wproj   = (f16*)alloc((size_t)256 * 256 * 2);
  f16* qkv     = (f16*)alloc((size_t)50176 * 768 * 2);
  float* posb  = (float*)alloc((size_t)8 * NAP * NTOK * 4);
  float* agb   = (float*)alloc((size_t)8 * NAP * NTOK * 4);
  f16* agent   = (f16*)alloc((size_t)128 * NAP * 32 * 2);
  float* tw    = (float*)alloc((size_t)128 * NTOK * 4);
  int* topidx  = (int*)alloc((size_t)128 * TTOP * 4);
  f16* vt      = (f16*)alloc((size_t)128 * 32 * NTOK * 2);
  float* agv   = (float*)alloc((size_t)128 * NA * 32 * 4);
  f16* pre     = (f16*)alloc((size_t)50176 * 256 * 2);
  f16* P       = (f16*)alloc((size_t)128 * PBH * 2);
  float* ssumg = tw;       // tw dead after k_topk
  f16* xh      = P;        // P region dead until k_psm; xh dead after qkv GEMM

  k_prep_w<<<1024, 256, 0, stream>>>(Wq, Wkv, Wproj, wqkv, wproj);
  k_cvt_x<<<2048, 256, 0, stream>>>(x, xh, (long)50176 * 256);
  k_bias<<<dim3(13, 8), 256, 0, stream>>>(an_b, na_b, ah_b, aw_b, ha_b, wa_b, posb, agb);
  k_gemm<false><<<2352, 256, 0, stream>>>(xh, wqkv, qkv, nullptr, nullptr, 768);
  k_pool_tw<<<128, 256, 0, stream>>>(qkv, agent, tw);
  k_topk<<<128, 1024, 0, stream>>>(tw, topidx);
  k_vt<<<dim3(49, 128), 256, 0, stream>>>(qkv, vt);
  k_flash<<<128, 256, 0, stream>>>(qkv, agent, vt, posb, agv);
  k_psm<<<dim3(13, 128), 256, 0, stream>>>(qkv, agent, topidx, agb, P, ssumg);
  k_out<<<dim3(13, 128), 256, 0, stream>>>(P, ssumg, agv, qkv, dwc_w, dwc_b, pre);
  k_gemm<true><<<784, 256, 0, stream>>>(pre, wproj, nullptr, (float*)d_out, bproj, 256);
}

// Round 8
// 311.358 us; speedup vs baseline: 1.5862x; 1.0604x over previous
//
#include <hip/hip_runtime.h>
#include <stdint.h>

typedef _Float16 f16;
typedef _Float16 half8 __attribute__((ext_vector_type(8)));
typedef float f32x4 __attribute__((ext_vector_type(4)));

#define NBATCH 16
#define NTOK 3136
#define NH 8
#define NA 49
#define NAP 64
#define TTOP 1568
#define QLD 768
#define NTILES 196          // NTOK/16
#define PBH 200704          // NTILES*8*16*8 f16 elements per bh
#define SCALE 0.17677669529663687f

__device__ __forceinline__ f32x4 mfma16(half8 a, half8 b, f32x4 c) {
  return __builtin_amdgcn_mfma_f32_16x16x32_f16(a, b, c, 0, 0, 0);
}

// global -> LDS direct DMA, 16B per lane. LDS dest is wave-uniform base + lane*16.
__device__ __forceinline__ void gload16(const void* g, void* l) {
  __builtin_amdgcn_global_load_lds(
      (const __attribute__((address_space(1))) void*)g,
      (__attribute__((address_space(3))) void*)l, 16, 0, 0);
}

// ---------------- weight conversion ----------------
__global__ __launch_bounds__(256) void k_prep_w(const float* Wq, const float* Wkv, const float* Wproj,
                                                f16* wqkv, f16* wproj) {
  int total1 = 768 * 256;
  int total = total1 + 256 * 256;
  for (int i = blockIdx.x * 256 + threadIdx.x; i < total; i += gridDim.x * 256) {
    if (i < total1) {
      int j = i >> 8, k = i & 255;
      float v = (j < 256) ? Wq[j * 256 + k] : Wkv[(j - 256) * 256 + k];
      wqkv[i] = (f16)v;
    } else {
      int i2 = i - total1;
      wproj[i2] = (f16)Wproj[i2];
    }
  }
}

// ---------------- x f32 -> f16 ----------------
__global__ __launch_bounds__(256) void k_cvt_x(const float* x, f16* xh, long total) {
  long i = (long)blockIdx.x * blockDim.x + threadIdx.x;
  long stride = (long)gridDim.x * blockDim.x;
  for (long e = i * 8; e < total; e += stride * 8) {
    float4 v0 = *(const float4*)(x + e);
    float4 v1 = *(const float4*)(x + e + 4);
    half8 o = {(f16)v0.x, (f16)v0.y, (f16)v0.z, (f16)v0.w,
               (f16)v1.x, (f16)v1.y, (f16)v1.z, (f16)v1.w};
    *(half8*)(xh + e) = o;
  }
}

// ---------------- bias precompute ----------------
__global__ __launch_bounds__(256) void k_bias(const float* an_b, const float* na_b,
                                              const float* ah_b, const float* aw_b,
                                              const float* ha_b, const float* wa_b,
                                              float* pos_bias, float* agent_bias) {
  int n = blockIdx.x * 256 + threadIdx.x;
  int h = blockIdx.y;
  if (n >= NTOK) return;
  int y = n / 56, x = n - y * 56;
  float py = (y + 0.5f) * 0.125f - 0.5f;
  float px = (x + 0.5f) * 0.125f - 0.5f;
  int iy0 = (int)floorf(py); float fy = py - (float)iy0;
  int ix0 = (int)floorf(px); float fx = px - (float)ix0;
  int y0 = max(iy0, 0), y1 = min(iy0 + 1, 6);
  int x0 = max(ix0, 0), x1 = min(ix0 + 1, 6);
  float w00 = (1.f - fy) * (1.f - fx), w01 = (1.f - fy) * fx;
  float w10 = fy * (1.f - fx), w11 = fy * fx;
  for (int a = 0; a < NA; ++a) {
    const float* pa = an_b + (h * NA + a) * 49;
    float up_an = w00 * pa[y0 * 7 + x0] + w01 * pa[y0 * 7 + x1] +
                  w10 * pa[y1 * 7 + x0] + w11 * pa[y1 * 7 + x1];
    const float* pn = na_b + (h * NA + a) * 49;
    float up_na = w00 * pn[y0 * 7 + x0] + w01 * pn[y0 * 7 + x1] +
                  w10 * pn[y1 * 7 + x0] + w11 * pn[y1 * 7 + x1];
    float pb = up_an + ah_b[(h * NA + a) * 56 + y] + aw_b[(h * NA + a) * 56 + x];
    pos_bias[((size_t)(h * NAP + a)) * NTOK + n] = pb;
    float ab = up_na + ha_b[(h * 56 + y) * NA + a] + wa_b[(h * 56 + x) * NA + a];
    agent_bias[((size_t)(h * NAP + a)) * NTOK + n] = ab;
  }
  for (int a = NA; a < NAP; ++a)
    pos_bias[((size_t)(h * NAP + a)) * NTOK + n] = 0.f;
}

// ---------------- f16 MFMA GEMM (m97 structure): C[M,N] = A[M,256] * Bw[N,256]^T ----------------
template <bool PROJ>
__global__ __launch_bounds__(256) void k_gemm(const f16* __restrict__ A, const f16* __restrict__ Bw,
                                              f16* __restrict__ Cf16, float* __restrict__ Cf32,
                                              const float* __restrict__ bias, int N) {
  __shared__ __align__(16) char lds[16384];   // A 8KB | B 8KB, rows linear 64B
  int per = gridDim.x >> 3;
  int wrk = (blockIdx.x & 7) * per + (blockIdx.x >> 3);
  int nNT = N >> 7;
  int mt = wrk / nNT, nt = wrk - mt * nNT;
  int m0 = mt * 128, n0 = nt * 128;
  int tid = threadIdx.x, w = tid >> 6, l = tid & 63, lr = l & 15, lg = l >> 4;
  int wm = w >> 1, wn = w & 1;
  f32x4 acc[4][4] = {};
  const char* Ab = (const char*)A + (size_t)m0 * 512;
  const char* Bb = (const char*)Bw + (size_t)n0 * 512;
  int rowA0 = 32 * w + (l >> 2);
  int rowA1 = rowA0 + 16;
  int koff = (l & 3) * 16;
  char* ldsA0 = lds + (2 * w) * 1024;
  char* ldsA1 = lds + (2 * w + 1) * 1024;
  char* ldsB0 = lds + 8192 + (2 * w) * 1024;
  char* ldsB1 = lds + 8192 + (2 * w + 1) * 1024;

  for (int k0 = 0; k0 < 256; k0 += 32) {
    gload16(Ab + (size_t)rowA0 * 512 + k0 * 2 + koff, ldsA0);
    gload16(Ab + (size_t)rowA1 * 512 + k0 * 2 + koff, ldsA1);
    gload16(Bb + (size_t)rowA0 * 512 + k0 * 2 + koff, ldsB0);
    gload16(Bb + (size_t)rowA1 * 512 + k0 * 2 + koff, ldsB1);
    __syncthreads();
    half8 af[4], bf[4];
#pragma unroll
    for (int m4 = 0; m4 < 4; ++m4) {
      int row = wm * 64 + m4 * 16 + lr;
      af[m4] = *(const half8*)(lds + row * 64 + lg * 16);
    }
#pragma unroll
    for (int n4 = 0; n4 < 4; ++n4) {
      int row = wn * 64 + n4 * 16 + lr;
      bf[n4] = *(const half8*)(lds + 8192 + row * 64 + lg * 16);
    }
#pragma unroll
    for (int m4 = 0; m4 < 4; ++m4)
#pragma unroll
      for (int n4 = 0; n4 < 4; ++n4)
        acc[m4][n4] = mfma16(af[m4], bf[n4], acc[m4][n4]);
    __syncthreads();
  }

#pragma unroll
  for (int m4 = 0; m4 < 4; ++m4)
#pragma unroll
    for (int n4 = 0; n4 < 4; ++n4)
#pragma unroll
      for (int r = 0; r < 4; ++r) {
        int m = m0 + wm * 64 + m4 * 16 + lg * 4 + r;
        int n = n0 + wn * 64 + n4 * 16 + lr;
        if (PROJ)
          Cf32[(size_t)m * N + n] = acc[m4][n4][r] + bias[n];
        else
          Cf16[(size_t)m * N + n] = (f16)acc[m4][n4][r];
      }
}

// ---------------- agent pooling (scaled) + token means ----------------
__global__ __launch_bounds__(256) void k_pool_tw(const f16* qkv, f16* agent, float* tw) {
  int bh = blockIdx.x, b = bh >> 3, h = bh & 7;
  int tid = threadIdx.x;
  for (int s = tid; s < NAP * 32; s += 256) {
    int a = s >> 5, d = s & 31;
    float val = 0.f;
    if (a < NA) {
      int dh = a / 7, dwi = a - dh * 7;
      float sum = 0.f;
      for (int i = 0; i < 8; ++i)
        for (int j = 0; j < 8; ++j) {
          int n = (dh * 8 + i) * 56 + dwi * 8 + j;
          sum += (float)qkv[((size_t)(b * NTOK + n)) * QLD + h * 32 + d];
        }
      val = sum * (SCALE / 64.f);
    }
    agent[(size_t)bh * NAP * 32 + s] = (f16)val;
  }
  for (int n = tid; n < NTOK; n += 256) {
    const half8* qp = (const half8*)(qkv + ((size_t)(b * NTOK + n)) * QLD + h * 32);
    float sum = 0.f;
#pragma unroll
    for (int j = 0; j < 4; ++j) {
      half8 v = qp[j];
#pragma unroll
      for (int e = 0; e < 8; ++e) sum += (float)v[e];
    }
    tw[(size_t)bh * NTOK + n] = sum * (1.f / 32.f);
  }
}

// ---------------- exact top-k (desc value, asc index) via bitonic sort ----------------
__global__ __launch_bounds__(1024) void k_topk(const float* tw, int* topidx) {
  __shared__ unsigned long long keys[4096];
  int bh = blockIdx.x, tid = threadIdx.x;
  const float* p = tw + (size_t)bh * NTOK;
  for (int s = tid; s < 4096; s += 1024) {
    float v = (s < NTOK) ? p[s] : -1e30f;
    unsigned ub = __float_as_uint(v);
    ub = (ub & 0x80000000u) ? ~ub : (ub | 0x80000000u);
    unsigned low = (s < NTOK) ? ~(unsigned)s : 0u;
    keys[s] = ((unsigned long long)ub << 32) | low;
  }
  for (int k = 2; k <= 4096; k <<= 1)
    for (int j = k >> 1; j > 0; j >>= 1) {
      __syncthreads();
      for (int i = tid; i < 4096; i += 1024) {
        int ixj = i ^ j;
        if (ixj > i) {
          unsigned long long a = keys[i], c = keys[ixj];
          bool lt = a < c;
          bool descRegion = ((i & k) == 0);
          if (lt == descRegion) { keys[i] = c; keys[ixj] = a; }
        }
      }
    }
  __syncthreads();
  for (int t = tid; t < TTOP; t += 1024)
    topidx[(size_t)bh * TTOP + t] = (int)(~(unsigned)keys[t]);
}

// ---------------- v transpose: vt[bh][d=32][n=3136] ----------------
__global__ __launch_bounds__(256) void k_vt(const f16* qkv, f16* vt) {
  __shared__ f16 t[64][33];
  int bh = blockIdx.y, b = bh >> 3, h = bh & 7;
  int n0 = blockIdx.x * 64;
  int tid = threadIdx.x;
  for (int s = tid; s < 64 * 32; s += 256) {
    int nl = s >> 5, d = s & 31;
    t[nl][d] = qkv[((size_t)(b * NTOK + n0 + nl)) * QLD + 512 + h * 32 + d];
  }
  __syncthreads();
  for (int s = tid; s < 64 * 32; s += 256) {
    int d = s >> 6, nl = s & 63;
    vt[((size_t)(bh * 32 + d)) * NTOK + n0 + nl] = t[nl][d];
  }
}

// ---------------- fused agent attention: softmax_n(agent_s . k^T + bias) @ v ----------------
__global__ __launch_bounds__(256) void k_flash(const f16* qkv, const f16* agent, const f16* vt,
                                               const float* pos_bias, float* agent_v) {
  __shared__ __align__(16) f16 pbuf[4][64][40];
  __shared__ float ored[64][33];
  __shared__ float rssum[64];
  int bh = blockIdx.x, b = bh >> 3, h = bh & 7;
  int tid = threadIdx.x, w = tid >> 6, l = tid & 63, lr = l & 15, lg = l >> 4;
  half8 afrag[4];
#pragma unroll
  for (int mt = 0; mt < 4; ++mt)
    afrag[mt] = *(const half8*)(agent + ((size_t)bh * 64 + mt * 16 + lr) * 32 + lg * 8);
  f32x4 o[4][2] = {};
  float rs[4][4] = {};
  const f16* kbase = qkv + (size_t)b * NTOK * QLD + 256 + h * 32;
  const f16* vtb = vt + (size_t)bh * 32 * NTOK;
  const float* pbb = pos_bias + (size_t)h * NAP * NTOK;
  f32x4 zero = {};
  for (int n0 = w * 32; n0 < NTOK; n0 += 128) {
#pragma unroll
    for (int t2 = 0; t2 < 2; ++t2) {
      int nc = n0 + t2 * 16;
      half8 kf = *(const half8*)(kbase + (size_t)(nc + lr) * QLD + lg * 8);
#pragma unroll
      for (int mt = 0; mt < 4; ++mt) {
        f32x4 s = mfma16(afrag[mt], kf, zero);
#pragma unroll
        for (int r = 0; r < 4; ++r) {
          int a = mt * 16 + lg * 4 + r;
          float pv = __expf(s[r] + pbb[(size_t)a * NTOK + nc + lr]);
          rs[mt][r] += pv;
          pbuf[w][a][t2 * 16 + lr] = (f16)pv;
        }
      }
    }
    half8 pf[4];
#pragma unroll
    for (int mt = 0; mt < 4; ++mt)
      pf[mt] = *(const half8*)(&pbuf[w][mt * 16 + lr][lg * 8]);
#pragma unroll
    for (int dt = 0; dt < 2; ++dt) {
      half8 vf = *(const half8*)(vtb + (size_t)(dt * 16 + lr) * NTOK + n0 + lg * 8);
#pragma unroll
      for (int mt = 0; mt < 4; ++mt)
        o[mt][dt] = mfma16(pf[mt], vf, o[mt][dt]);
    }
  }
#pragma unroll
  for (int mt = 0; mt < 4; ++mt)
#pragma unroll
    for (int r = 0; r < 4; ++r) {
      float v = rs[mt][r];
      for (int off = 1; off < 16; off <<= 1) v += __shfl_xor(v, off, 64);
      rs[mt][r] = v;
    }
  for (int s = tid; s < 64 * 33; s += 256) ((float*)ored)[s] = 0.f;
  if (tid < 64) rssum[tid] = 0.f;
  __syncthreads();
  for (int ww = 0; ww < 4; ++ww) {
    if (w == ww) {
      if (lr == 0)
#pragma unroll
        for (int mt = 0; mt < 4; ++mt)
#pragma unroll
          for (int r = 0; r < 4; ++r) rssum[mt * 16 + lg * 4 + r] += rs[mt][r];
#pragma unroll
      for (int mt = 0; mt < 4; ++mt)
#pragma unroll
        for (int dt = 0; dt < 2; ++dt)
#pragma unroll
          for (int r = 0; r < 4; ++r)
            ored[mt * 16 + lg * 4 + r][dt * 16 + lr] += o[mt][dt][r];
    }
    __syncthreads();
  }
  for (int s = tid; s < NA * 32; s += 256) {
    int a = s >> 5, d = s & 31;
    agent_v[(size_t)bh * NA * 32 + s] = ored[a][d] / rssum[a];
  }
}

// ---------------- k_psm: q2 gather-MFMA -> resize -> exp -> P (fragment layout) + ssum ----------------
__global__ __launch_bounds__(256) void k_psm(const f16* qkv, const f16* agent, const int* topidx,
                                             const float* agent_bias, f16* P, float* ssumg) {
  __shared__ __align__(16) f16 q2buf[144][88];
  int chunk = blockIdx.x, bh = blockIdx.y, b = bh >> 3, h = bh & 7;
  int tid = threadIdx.x, w = tid >> 6, l = tid & 63, lr = l & 15, lg = l >> 4;
  half8 bfrag[4];
#pragma unroll
  for (int nt = 0; nt < 4; ++nt)
    bfrag[nt] = *(const half8*)(agent + ((size_t)bh * 64 + nt * 16 + lr) * 32 + lg * 8);
  int jbase = chunk * 128 - 8;
  f32x4 zero = {};
  for (int mt = w; mt < 9; mt += 4) {
    int j = jbase + mt * 16 + lr;
    int jc = min(max(j, 0), TTOP - 1);
    int tok = topidx[(size_t)bh * TTOP + jc];
    half8 qf = *(const half8*)(qkv + ((size_t)(b * NTOK + tok)) * QLD + h * 32 + lg * 8);
#pragma unroll
    for (int nt = 0; nt < 4; ++nt) {
      f32x4 s = mfma16(qf, bfrag[nt], zero);
#pragma unroll
      for (int r = 0; r < 4; ++r)
        q2buf[mt * 16 + lg * 4 + r][nt * 16 + lr] = (f16)s[r];
    }
  }
  __syncthreads();
  int g = chunk * 256 + tid;
  if (g >= NTOK) return;
  int hi = g >> 1;
  int jA, jB; float wAq, wBq;
  if (g & 1) { jA = hi; jB = hi + 1; wAq = 0.75f; wBq = 0.25f; }
  else       { jA = hi - 1; jB = hi; wAq = 0.25f; wBq = 0.75f; }
  jA = min(max(jA, 0), TTOP - 1);
  jB = min(max(jB, 0), TTOP - 1);
  int lA = jA - jbase, lB = jB - jbase;
  const float* ab = agent_bias + (size_t)h * NAP * NTOK + g;
  f16* Pb = P + (size_t)bh * PBH;
  int tile = g >> 4, lrr = g & 15;
  float ssum = 0.f;
#pragma unroll
  for (int c = 0; c < 7; ++c) {
    half8 a8 = *(const half8*)(&q2buf[lA][c * 8]);
    half8 b8 = *(const half8*)(&q2buf[lB][c * 8]);
    half8 o;
#pragma unroll
    for (int e = 0; e < 8; ++e) {
      int a = c * 8 + e;
      float pv = 0.f;
      if (a < NA) {
        float v = wAq * (float)a8[e] + wBq * (float)b8[e] + ab[(size_t)a * NTOK];
        pv = __expf(v);
        ssum += pv;
      }
      o[e] = (f16)pv;
    }
    *(half8*)(Pb + ((size_t)(tile * 8 + c) * 16 + lrr) * 8) = o;
  }
  half8 z = {};
  *(half8*)(Pb + ((size_t)(tile * 8 + 7) * 16 + lrr) * 8) = z;
  ssumg[(size_t)bh * NTOK + g] = ssum;
}

// ---------------- k_out: C = (P @ avT)/ssum + dwconv (LDS-staged v), write pre ----------------
// chunk = 224 tokens = exactly 4 image rows. Phase A: MFMA P@avT -> ctile.
// Phase B: stage v rows y0-1..y0+4 coalesced into vtile (80B/token -> conflict-free b128).
// Phase C: per-token epilogue entirely from LDS.
__global__ __launch_bounds__(256) void k_out(const f16* __restrict__ P, const float* __restrict__ ssumg,
                                             const float* __restrict__ agent_v,
                                             const f16* __restrict__ qkv,
                                             const float* __restrict__ dwc_w,
                                             const float* __restrict__ dwc_b,
                                             f16* __restrict__ pre) {
  __shared__ __align__(16) f16 avT[32][72];
  __shared__ __align__(16) f16 ctile[224][40];
  __shared__ __align__(16) f16 vtile[6][56][40];   // [row][token][32 data + 8 pad]
  __shared__ float wconv[9][32];
  __shared__ float bconv[32];
  int chunk = blockIdx.x, bh = blockIdx.y, b = bh >> 3, h = bh & 7;
  int tid = threadIdx.x, w = tid >> 6, l = tid & 63, lr = l & 15, lg = l >> 4;
  int y0 = chunk * 4;
  // ---- issue v-stage global loads early (regs), they complete under phase A ----
  half8 sv[6];
  bool svok[6];
#pragma unroll
  for (int i = 0; i < 6; ++i) {
    int s = tid + i * 256;
    int ry = s / 224, rem = s % 224;
    int tok = rem >> 2, c = rem & 3;
    int gy = y0 - 1 + ry;
    svok[i] = (s < 1344) && (gy >= 0) && (gy < 56);
    if (svok[i])
      sv[i] = *(const half8*)(qkv + ((size_t)(b * NTOK + gy * 56 + tok)) * QLD + 512 + h * 32 + c * 8);
  }
  // ---- stage small tables ----
  for (int s = tid; s < 32 * 64; s += 256) {
    int d = s >> 6, a = s & 63;
    avT[d][a] = (a < NA) ? (f16)agent_v[((size_t)bh * NA + a) * 32 + d] : (f16)0.f;
  }
  for (int s = tid; s < 32 * 9; s += 256) {
    int d = s / 9, t = s - d * 9;
    wconv[t][d] = dwc_w[(size_t)(h * 32 + d) * 9 + t];
  }
  if (tid < 32) bconv[tid] = dwc_b[h * 32 + tid];
  __syncthreads();
  // ---- phase A: MFMA P @ avT ----
  half8 bf[2][2];
#pragma unroll
  for (int nt = 0; nt < 2; ++nt)
#pragma unroll
    for (int ks = 0; ks < 2; ++ks)
      bf[nt][ks] = *(const half8*)(&avT[0][0] + (size_t)(nt * 16 + lr) * 72 + ks * 32 + lg * 8);
  const f16* Pb = P + (size_t)bh * PBH;
#pragma unroll
  for (int i = 0; i < 4; ++i) {
    int lt = w * 4 + i;
    if (lt >= 14) continue;
    int tile = chunk * 14 + lt;
    const f16* Pt = Pb + (size_t)tile * 1024;
    half8 a0 = *(const half8*)(Pt + ((size_t)(0 + lg) * 16 + lr) * 8);
    half8 a1 = *(const half8*)(Pt + ((size_t)(4 + lg) * 16 + lr) * 8);
    f32x4 acc0 = {}, acc1 = {};
    acc0 = mfma16(a0, bf[0][0], acc0);
    acc0 = mfma16(a1, bf[0][1], acc0);
    acc1 = mfma16(a0, bf[1][0], acc1);
    acc1 = mfma16(a1, bf[1][1], acc1);
    int ltrow = lt * 16 + lg * 4;
#pragma unroll
    for (int r = 0; r < 4; ++r) {
      float ss = ssumg[(size_t)bh * NTOK + tile * 16 + lg * 4 + r];
      float inv = 1.f / ss;
      ctile[ltrow + r][lr] = (f16)(acc0[r] * inv);
      ctile[ltrow + r][16 + lr] = (f16)(acc1[r] * inv);
    }
  }
  // ---- phase B: write staged v into vtile ----
#pragma unroll
  for (int i = 0; i < 6; ++i) {
    if (svok[i]) {
      int s = tid + i * 256;
      int ry = s / 224, rem = s % 224;
      int tok = rem >> 2, c = rem & 3;
      *(half8*)(&vtile[ry][tok][c * 8]) = sv[i];
    }
  }
  __syncthreads();
  // ---- phase C: epilogue per token ----
  if (tid >= 224) return;
  int g = chunk * 224 + tid;
  int ly = tid / 56, x = tid % 56;
  int y = y0 + ly;
  float accd[32];
#pragma unroll
  for (int c = 0; c < 4; ++c) {
    half8 cv = *(const half8*)(&ctile[tid][c * 8]);
#pragma unroll
    for (int e = 0; e < 8; ++e) accd[c * 8 + e] = (float)cv[e] + bconv[c * 8 + e];
  }
#pragma unroll
  for (int ky = 0; ky < 3; ++ky) {
    int gy = y + ky - 1;
    if (gy < 0 || gy >= 56) continue;
    int ry = ly + ky;   // gy - (y0-1)
#pragma unroll
    for (int kx = 0; kx < 3; ++kx) {
      int xx = x + kx - 1;
      if (xx < 0 || xx >= 56) continue;
      int t = ky * 3 + kx;
#pragma unroll
      for (int c = 0; c < 4; ++c) {
        half8 vv = *(const half8*)(&vtile[ry][xx][c * 8]);
#pragma unroll
        for (int e = 0; e < 8; ++e) accd[c * 8 + e] += wconv[t][c * 8 + e] * (float)vv[e];
      }
    }
  }
  f16* op = pre + ((size_t)(b * NTOK + g)) * 256 + h * 32;
#pragma unroll
  for (int c = 0; c < 4; ++c) {
    half8 o;
#pragma unroll
    for (int e = 0; e < 8; ++e) o[e] = (f16)accd[c * 8 + e];
    *(half8*)(op + c * 8) = o;
  }
}

extern "C" void kernel_launch(void* const* d_in, const int* in_sizes, int n_in,
                              void* d_out, int out_size, void* d_ws, size_t ws_size,
                              hipStream_t stream) {
  const float* x     = (const float*)d_in[0];
  const float* Wq    = (const float*)d_in[3];
  const float* Wkv   = (const float*)d_in[4];
  const float* Wproj = (const float*)d_in[5];
  const float* bproj = (const float*)d_in[6];
  const float* dwc_w = (const float*)d_in[7];
  const float* dwc_b = (const float*)d_in[8];
  const float* an_b  = (const float*)d_in[9];
  const float* na_b  = (const float*)d_in[10];
  const float* ah_b  = (const float*)d_in[11];
  const float* aw_b  = (const float*)d_in[12];
  const float* ha_b  = (const float*)d_in[13];
  const float* wa_b  = (const float*)d_in[14];

  char* ws = (char*)d_ws;
  size_t off = 0;
  auto alloc = [&](size_t bytes) {
    void* p = ws + off;
    off = (off + bytes + 255) & ~(size_t)255;
    return p;
  };
  f16* wqkv    = (f16*)alloc((size_t)768 * 256 * 2);
  f16* wproj   = (f16*)alloc((size_t)256 * 256 * 2);
  f16* qkv     = (f16*)alloc((size_t)50176 * 768 * 2);
  float* posb  = (float*)alloc((size_t)8 * NAP * NTOK * 4);
  float* agb   = (float*)alloc((size_t)8 * NAP * NTOK * 4);
  f16* agent   = (f16*)alloc((size_t)128 * NAP * 32 * 2);
  float* tw    = (float*)alloc((size_t)128 * NTOK * 4);
  int* topidx  = (int*)alloc((size_t)128 * TTOP * 4);
  f16* vt      = (f16*)alloc((size_t)128 * 32 * NTOK * 2);
  float* agv   = (float*)alloc((size_t)128 * NA * 32 * 4);
  f16* pre     = (f16*)alloc((size_t)50176 * 256 * 2);
  f16* P       = (f16*)alloc((size_t)128 * PBH * 2);
  float* ssumg = tw;       // tw dead after k_topk
  f16* xh      = P;        // P region dead until k_psm; xh dead after qkv GEMM

  k_prep_w<<<1024, 256, 0, stream>>>(Wq, Wkv, Wproj, wqkv, wproj);
  k_cvt_x<<<2048, 256, 0, stream>>>(x, xh, (long)50176 * 256);
  k_bias<<<dim3(13, 8), 256, 0, stream>>>(an_b, na_b, ah_b, aw_b, ha_b, wa_b, posb, agb);
  k_gemm<false><<<2352, 256, 0, stream>>>(xh, wqkv, qkv, nullptr, nullptr, 768);
  k_pool_tw<<<128, 256, 0, stream>>>(qkv, agent, tw);
  k_topk<<<128, 1024, 0, stream>>>(tw, topidx);
  k_vt<<<dim3(49, 128), 256, 0, stream>>>(qkv, vt);
  k_flash<<<128, 256, 0, stream>>>(qkv, agent, vt, posb, agv);
  k_psm<<<dim3(13, 128), 256, 0, stream>>>(qkv, agent, topidx, agb, P, ssumg);
  k_out<<<dim3(14, 128), 256, 0, stream>>>(P, ssumg, agv, qkv, dwc_w, dwc_b, pre);
  k_gemm<true><<<784, 256, 0, stream>>>(pre, wproj, nullptr, (float*)d_out, bproj, 256);
}

// Round 9
// 282.394 us; speedup vs baseline: 1.7489x; 1.1026x over previous
//
#include <hip/hip_runtime.h>
#include <stdint.h>

typedef _Float16 f16;
typedef _Float16 half8 __attribute__((ext_vector_type(8)));
typedef float f32x4 __attribute__((ext_vector_type(4)));

#define NBATCH 16
#define NTOK 3136
#define NTOT 50176          // NBATCH*NTOK
#define NH 8
#define NA 49
#define NAP 64
#define TTOP 1568
#define NTILES 196          // NTOK/16
#define PBH 200704          // NTILES*8*16*8 f16 elements per bh
#define SCALE 0.17677669529663687f

__device__ __forceinline__ f32x4 mfma16(half8 a, half8 b, f32x4 c) {
  return __builtin_amdgcn_mfma_f32_16x16x32_f16(a, b, c, 0, 0, 0);
}

__device__ __forceinline__ void gload16(const void* g, void* l) {
  __builtin_amdgcn_global_load_lds(
      (const __attribute__((address_space(1))) void*)g,
      (__attribute__((address_space(3))) void*)l, 16, 0, 0);
}

// ---------------- weight conversion ----------------
__global__ __launch_bounds__(256) void k_prep_w(const float* Wq, const float* Wkv, const float* Wproj,
                                                f16* wqkv, f16* wproj) {
  int total1 = 768 * 256;
  int total = total1 + 256 * 256;
  for (int i = blockIdx.x * 256 + threadIdx.x; i < total; i += gridDim.x * 256) {
    if (i < total1) {
      int j = i >> 8, k = i & 255;
      float v = (j < 256) ? Wq[j * 256 + k] : Wkv[(j - 256) * 256 + k];
      wqkv[i] = (f16)v;
    } else {
      int i2 = i - total1;
      wproj[i2] = (f16)Wproj[i2];
    }
  }
}

// ---------------- x f32 -> f16 ----------------
__global__ __launch_bounds__(256) void k_cvt_x(const float* x, f16* xh, long total) {
  long i = (long)blockIdx.x * blockDim.x + threadIdx.x;
  long stride = (long)gridDim.x * blockDim.x;
  for (long e = i * 8; e < total; e += stride * 8) {
    float4 v0 = *(const float4*)(x + e);
    float4 v1 = *(const float4*)(x + e + 4);
    half8 o = {(f16)v0.x, (f16)v0.y, (f16)v0.z, (f16)v0.w,
               (f16)v1.x, (f16)v1.y, (f16)v1.z, (f16)v1.w};
    *(half8*)(xh + e) = o;
  }
}

// ---------------- bias precompute ----------------
__global__ __launch_bounds__(256) void k_bias(const float* an_b, const float* na_b,
                                              const float* ah_b, const float* aw_b,
                                              const float* ha_b, const float* wa_b,
                                              float* pos_bias, float* agent_bias) {
  int n = blockIdx.x * 256 + threadIdx.x;
  int h = blockIdx.y;
  if (n >= NTOK) return;
  int y = n / 56, x = n - y * 56;
  float py = (y + 0.5f) * 0.125f - 0.5f;
  float px = (x + 0.5f) * 0.125f - 0.5f;
  int iy0 = (int)floorf(py); float fy = py - (float)iy0;
  int ix0 = (int)floorf(px); float fx = px - (float)ix0;
  int y0 = max(iy0, 0), y1 = min(iy0 + 1, 6);
  int x0 = max(ix0, 0), x1 = min(ix0 + 1, 6);
  float w00 = (1.f - fy) * (1.f - fx), w01 = (1.f - fy) * fx;
  float w10 = fy * (1.f - fx), w11 = fy * fx;
  for (int a = 0; a < NA; ++a) {
    const float* pa = an_b + (h * NA + a) * 49;
    float up_an = w00 * pa[y0 * 7 + x0] + w01 * pa[y0 * 7 + x1] +
                  w10 * pa[y1 * 7 + x0] + w11 * pa[y1 * 7 + x1];
    const float* pn = na_b + (h * NA + a) * 49;
    float up_na = w00 * pn[y0 * 7 + x0] + w01 * pn[y0 * 7 + x1] +
                  w10 * pn[y1 * 7 + x0] + w11 * pn[y1 * 7 + x1];
    float pb = up_an + ah_b[(h * NA + a) * 56 + y] + aw_b[(h * NA + a) * 56 + x];
    pos_bias[((size_t)(h * NAP + a)) * NTOK + n] = pb;
    float ab = up_na + ha_b[(h * 56 + y) * NA + a] + wa_b[(h * 56 + x) * NA + a];
    agent_bias[((size_t)(h * NAP + a)) * NTOK + n] = ab;
  }
  for (int a = NA; a < NAP; ++a)
    pos_bias[((size_t)(h * NAP + a)) * NTOK + n] = 0.f;
}

// ---------------- f16 MFMA GEMM (m97 structure) ----------------
// !PROJ: A = xh [m][256], C -> qkvH planes [(n>>5)][m][n&31]
//  PROJ: A = preH planes [k0>>5][m][32] (contiguous 8KB slab per K-step), C -> f32 out + bias
template <bool PROJ>
__global__ __launch_bounds__(256) void k_gemm(const f16* __restrict__ A, const f16* __restrict__ Bw,
                                              f16* __restrict__ CH, float* __restrict__ Cf32,
                                              const float* __restrict__ bias, int N) {
  __shared__ __align__(16) char lds[16384];   // A 8KB | B 8KB, rows linear 64B
  int per = gridDim.x >> 3;
  int wrk = (blockIdx.x & 7) * per + (blockIdx.x >> 3);
  int nNT = N >> 7;
  int mt = wrk / nNT, nt = wrk - mt * nNT;
  int m0 = mt * 128, n0 = nt * 128;
  int tid = threadIdx.x, w = tid >> 6, l = tid & 63, lr = l & 15, lg = l >> 4;
  int wm = w >> 1, wn = w & 1;
  f32x4 acc[4][4] = {};
  const char* Bb = (const char*)Bw + (size_t)n0 * 512;
  int rowA0 = 32 * w + (l >> 2);
  int rowA1 = rowA0 + 16;
  int koff = (l & 3) * 16;
  char* ldsA0 = lds + (2 * w) * 1024;
  char* ldsA1 = lds + (2 * w + 1) * 1024;
  char* ldsB0 = lds + 8192 + (2 * w) * 1024;
  char* ldsB1 = lds + 8192 + (2 * w + 1) * 1024;

  for (int k0 = 0; k0 < 256; k0 += 32) {
    if (PROJ) {
      const char* Ab = (const char*)A + ((size_t)(k0 >> 5) * NTOT + m0) * 64;
      gload16(Ab + (size_t)rowA0 * 64 + koff, ldsA0);
      gload16(Ab + (size_t)rowA1 * 64 + koff, ldsA1);
    } else {
      const char* Ab = (const char*)A + (size_t)m0 * 512 + k0 * 2;
      gload16(Ab + (size_t)rowA0 * 512 + koff, ldsA0);
      gload16(Ab + (size_t)rowA1 * 512 + koff, ldsA1);
    }
    gload16(Bb + (size_t)rowA0 * 512 + k0 * 2 + koff, ldsB0);
    gload16(Bb + (size_t)rowA1 * 512 + k0 * 2 + koff, ldsB1);
    __syncthreads();
    half8 af[4], bf[4];
#pragma unroll
    for (int m4 = 0; m4 < 4; ++m4) {
      int row = wm * 64 + m4 * 16 + lr;
      af[m4] = *(const half8*)(lds + row * 64 + lg * 16);
    }
#pragma unroll
    for (int n4 = 0; n4 < 4; ++n4) {
      int row = wn * 64 + n4 * 16 + lr;
      bf[n4] = *(const half8*)(lds + 8192 + row * 64 + lg * 16);
    }
#pragma unroll
    for (int m4 = 0; m4 < 4; ++m4)
#pragma unroll
      for (int n4 = 0; n4 < 4; ++n4)
        acc[m4][n4] = mfma16(af[m4], bf[n4], acc[m4][n4]);
    __syncthreads();
  }

#pragma unroll
  for (int n4 = 0; n4 < 4; ++n4) {
    int n = n0 + wn * 64 + n4 * 16 + lr;
    f16* bp = PROJ ? nullptr : (CH + (size_t)(n >> 5) * NTOT * 32 + (n & 31));
#pragma unroll
    for (int m4 = 0; m4 < 4; ++m4)
#pragma unroll
      for (int r = 0; r < 4; ++r) {
        int m = m0 + wm * 64 + m4 * 16 + lg * 4 + r;
        if (PROJ)
          Cf32[(size_t)m * N + n] = acc[m4][n4][r] + bias[n];
        else
          bp[(size_t)m * 32] = (f16)acc[m4][n4][r];
      }
  }
}

// ---------------- agent pooling (scaled) + token means ----------------
__global__ __launch_bounds__(256) void k_pool_tw(const f16* qkvH, f16* agent, float* tw) {
  int bh = blockIdx.x, b = bh >> 3, h = bh & 7;
  int tid = threadIdx.x;
  const f16* qp0 = qkvH + ((size_t)h * NTOT + (size_t)b * NTOK) * 32;
  // pooling: thread = (a, c) ; a<64, c<4 (8-d chunk)
  {
    int a = tid >> 2, c = tid & 3;
    float s8[8] = {};
    if (a < NA) {
      int dh = a / 7, dwi = a - dh * 7;
      for (int i = 0; i < 8; ++i)
#pragma unroll
        for (int j = 0; j < 8; ++j) {
          int tok = (dh * 8 + i) * 56 + dwi * 8 + j;
          half8 v = *(const half8*)(qp0 + (size_t)tok * 32 + c * 8);
#pragma unroll
          for (int e = 0; e < 8; ++e) s8[e] += (float)v[e];
        }
    }
    half8 o;
#pragma unroll
    for (int e = 0; e < 8; ++e) o[e] = (f16)(s8[e] * (SCALE / 64.f));
    *(half8*)(agent + (size_t)bh * NAP * 32 + a * 32 + c * 8) = o;
  }
  for (int n = tid; n < NTOK; n += 256) {
    const half8* qp = (const half8*)(qp0 + (size_t)n * 32);
    float sum = 0.f;
#pragma unroll
    for (int j = 0; j < 4; ++j) {
      half8 v = qp[j];
#pragma unroll
      for (int e = 0; e < 8; ++e) sum += (float)v[e];
    }
    tw[(size_t)bh * NTOK + n] = sum * (1.f / 32.f);
  }
}

// ---------------- exact top-k (desc value, asc index) via bitonic sort ----------------
__global__ __launch_bounds__(1024) void k_topk(const float* tw, int* topidx) {
  __shared__ unsigned long long keys[4096];
  int bh = blockIdx.x, tid = threadIdx.x;
  const float* p = tw + (size_t)bh * NTOK;
  for (int s = tid; s < 4096; s += 1024) {
    float v = (s < NTOK) ? p[s] : -1e30f;
    unsigned ub = __float_as_uint(v);
    ub = (ub & 0x80000000u) ? ~ub : (ub | 0x80000000u);
    unsigned low = (s < NTOK) ? ~(unsigned)s : 0u;
    keys[s] = ((unsigned long long)ub << 32) | low;
  }
  for (int k = 2; k <= 4096; k <<= 1)
    for (int j = k >> 1; j > 0; j >>= 1) {
      __syncthreads();
      for (int i = tid; i < 4096; i += 1024) {
        int ixj = i ^ j;
        if (ixj > i) {
          unsigned long long a = keys[i], c = keys[ixj];
          bool lt = a < c;
          bool descRegion = ((i & k) == 0);
          if (lt == descRegion) { keys[i] = c; keys[ixj] = a; }
        }
      }
    }
  __syncthreads();
  for (int t = tid; t < TTOP; t += 1024)
    topidx[(size_t)bh * TTOP + t] = (int)(~(unsigned)keys[t]);
}

// ---------------- v transpose: vt[bh][d=32][n=3136] ----------------
__global__ __launch_bounds__(256) void k_vt(const f16* qkvH, f16* vt) {
  __shared__ __align__(16) f16 t[64][40];
  int bh = blockIdx.y, b = bh >> 3, h = bh & 7;
  int n0 = blockIdx.x * 64;
  int tid = threadIdx.x;
  const f16* vp = qkvH + ((size_t)(16 + h) * NTOT + (size_t)b * NTOK + n0) * 32;
  {
    int nl = tid >> 2, c = tid & 3;
    *(half8*)(&t[nl][c * 8]) = *(const half8*)(vp + (size_t)nl * 32 + c * 8);
  }
  __syncthreads();
  for (int s = tid; s < 64 * 32; s += 256) {
    int d = s >> 6, nl = s & 63;
    vt[((size_t)(bh * 32 + d)) * NTOK + n0 + nl] = t[nl][d];
  }
}

// ---------------- fused agent attention: softmax_n(agent_s . k^T + bias) @ v ----------------
__global__ __launch_bounds__(256) void k_flash(const f16* qkvH, const f16* agent, const f16* vt,
                                               const float* pos_bias, float* agent_v) {
  __shared__ __align__(16) f16 pbuf[4][64][40];
  __shared__ float ored[64][33];
  __shared__ float rssum[64];
  int bh = blockIdx.x, b = bh >> 3, h = bh & 7;
  int tid = threadIdx.x, w = tid >> 6, l = tid & 63, lr = l & 15, lg = l >> 4;
  half8 afrag[4];
#pragma unroll
  for (int mt = 0; mt < 4; ++mt)
    afrag[mt] = *(const half8*)(agent + ((size_t)bh * 64 + mt * 16 + lr) * 32 + lg * 8);
  f32x4 o[4][2] = {};
  float rs[4][4] = {};
  const f16* kbase = qkvH + ((size_t)(8 + h) * NTOT + (size_t)b * NTOK) * 32;
  const f16* vtb = vt + (size_t)bh * 32 * NTOK;
  const float* pbb = pos_bias + (size_t)h * NAP * NTOK;
  f32x4 zero = {};
  for (int n0 = w * 32; n0 < NTOK; n0 += 128) {
#pragma unroll
    for (int t2 = 0; t2 < 2; ++t2) {
      int nc = n0 + t2 * 16;
      half8 kf = *(const half8*)(kbase + (size_t)(nc + lr) * 32 + lg * 8);
#pragma unroll
      for (int mt = 0; mt < 4; ++mt) {
        f32x4 s = mfma16(afrag[mt], kf, zero);
#pragma unroll
        for (int r = 0; r < 4; ++r) {
          int a = mt * 16 + lg * 4 + r;
          float pv = __expf(s[r] + pbb[(size_t)a * NTOK + nc + lr]);
          rs[mt][r] += pv;
          pbuf[w][a][t2 * 16 + lr] = (f16)pv;
        }
      }
    }
    half8 pf[4];
#pragma unroll
    for (int mt = 0; mt < 4; ++mt)
      pf[mt] = *(const half8*)(&pbuf[w][mt * 16 + lr][lg * 8]);
#pragma unroll
    for (int dt = 0; dt < 2; ++dt) {
      half8 vf = *(const half8*)(vtb + (size_t)(dt * 16 + lr) * NTOK + n0 + lg * 8);
#pragma unroll
      for (int mt = 0; mt < 4; ++mt)
        o[mt][dt] = mfma16(pf[mt], vf, o[mt][dt]);
    }
  }
#pragma unroll
  for (int mt = 0; mt < 4; ++mt)
#pragma unroll
    for (int r = 0; r < 4; ++r) {
      float v = rs[mt][r];
      for (int off = 1; off < 16; off <<= 1) v += __shfl_xor(v, off, 64);
      rs[mt][r] = v;
    }
  for (int s = tid; s < 64 * 33; s += 256) ((float*)ored)[s] = 0.f;
  if (tid < 64) rssum[tid] = 0.f;
  __syncthreads();
  for (int ww = 0; ww < 4; ++ww) {
    if (w == ww) {
      if (lr == 0)
#pragma unroll
        for (int mt = 0; mt < 4; ++mt)
#pragma unroll
          for (int r = 0; r < 4; ++r) rssum[mt * 16 + lg * 4 + r] += rs[mt][r];
#pragma unroll
      for (int mt = 0; mt < 4; ++mt)
#pragma unroll
        for (int dt = 0; dt < 2; ++dt)
#pragma unroll
          for (int r = 0; r < 4; ++r)
            ored[mt * 16 + lg * 4 + r][dt * 16 + lr] += o[mt][dt][r];
    }
    __syncthreads();
  }
  for (int s = tid; s < NA * 32; s += 256) {
    int a = s >> 5, d = s & 31;
    agent_v[(size_t)bh * NA * 32 + s] = ored[a][d] / rssum[a];
  }
}

// ---------------- k_psm: q2 gather-MFMA -> resize -> exp -> normalized P (fragment layout) ----------------
__global__ __launch_bounds__(256) void k_psm(const f16* qkvH, const f16* agent, const int* topidx,
                                             const float* agent_bias, f16* P) {
  __shared__ __align__(16) f16 q2buf[144][88];
  int chunk = blockIdx.x, bh = blockIdx.y, b = bh >> 3, h = bh & 7;
  int tid = threadIdx.x, w = tid >> 6, l = tid & 63, lr = l & 15, lg = l >> 4;
  const f16* qplane = qkvH + ((size_t)h * NTOT + (size_t)b * NTOK) * 32;
  half8 bfrag[4];
#pragma unroll
  for (int nt = 0; nt < 4; ++nt)
    bfrag[nt] = *(const half8*)(agent + ((size_t)bh * 64 + nt * 16 + lr) * 32 + lg * 8);
  int jbase = chunk * 128 - 8;
  f32x4 zero = {};
  for (int mt = w; mt < 9; mt += 4) {
    int j = jbase + mt * 16 + lr;
    int jc = min(max(j, 0), TTOP - 1);
    int tok = topidx[(size_t)bh * TTOP + jc];
    half8 qf = *(const half8*)(qplane + (size_t)tok * 32 + lg * 8);
#pragma unroll
    for (int nt = 0; nt < 4; ++nt) {
      f32x4 s = mfma16(qf, bfrag[nt], zero);
#pragma unroll
      for (int r = 0; r < 4; ++r)
        q2buf[mt * 16 + lg * 4 + r][nt * 16 + lr] = (f16)s[r];
    }
  }
  __syncthreads();
  int g = chunk * 256 + tid;
  if (g >= NTOK) return;
  int hi = g >> 1;
  int jA, jB; float wAq, wBq;
  if (g & 1) { jA = hi; jB = hi + 1; wAq = 0.75f; wBq = 0.25f; }
  else       { jA = hi - 1; jB = hi; wAq = 0.25f; wBq = 0.75f; }
  jA = min(max(jA, 0), TTOP - 1);
  jB = min(max(jB, 0), TTOP - 1);
  int lA = jA - jbase, lB = jB - jbase;
  const float* ab = agent_bias + (size_t)h * NAP * NTOK + g;
  f16* Pb = P + (size_t)bh * PBH;
  int tile = g >> 4, lrr = g & 15;
  float ssum = 0.f;
  half8 oo[7];
#pragma unroll
  for (int c = 0; c < 7; ++c) {
    half8 a8 = *(const half8*)(&q2buf[lA][c * 8]);
    half8 b8 = *(const half8*)(&q2buf[lB][c * 8]);
#pragma unroll
    for (int e = 0; e < 8; ++e) {
      int a = c * 8 + e;
      float pv = 0.f;
      if (a < NA) {
        float v = wAq * (float)a8[e] + wBq * (float)b8[e] + ab[(size_t)a * NTOK];
        pv = __expf(v);
        ssum += pv;
      }
      oo[c][e] = (f16)pv;
    }
  }
  f16 invs = (f16)(1.f / ssum);
  half8 iv8 = {invs, invs, invs, invs, invs, invs, invs, invs};
#pragma unroll
  for (int c = 0; c < 7; ++c)
    *(half8*)(Pb + ((size_t)(tile * 8 + c) * 16 + lrr) * 8) = oo[c] * iv8;
  half8 z = {};
  *(half8*)(Pb + ((size_t)(tile * 8 + 7) * 16 + lrr) * 8) = z;
}

// ---------------- k_out: C = P @ avT + dwconv (LDS-staged v), write preH (coalesced) ----------------
__global__ __launch_bounds__(256) void k_out(const f16* __restrict__ P,
                                             const float* __restrict__ agent_v,
                                             const f16* __restrict__ qkvH,
                                             const float* __restrict__ dwc_w,
                                             const float* __restrict__ dwc_b,
                                             f16* __restrict__ preH) {
  __shared__ __align__(16) f16 avT[32][72];
  __shared__ __align__(16) f16 ctile[224][40];
  __shared__ __align__(16) f16 vtile[6][56][40];
  __shared__ float wconv[9][32];
  __shared__ float bconv[32];
  int chunk = blockIdx.x, bh = blockIdx.y, b = bh >> 3, h = bh & 7;
  int tid = threadIdx.x, w = tid >> 6, l = tid & 63, lr = l & 15, lg = l >> 4;
  int y0 = chunk * 4;
  const f16* vp = qkvH + ((size_t)(16 + h) * NTOT + (size_t)b * NTOK) * 32;
  // ---- front-issue ALL global loads ----
  // P fragments
  const f16* Pb = P + (size_t)bh * PBH;
  half8 pa0[4], pa1[4];
#pragma unroll
  for (int i = 0; i < 4; ++i) {
    int lt = w * 4 + i;
    if (lt < 14) {
      const f16* Pt = Pb + (size_t)(chunk * 14 + lt) * 1024;
      pa0[i] = *(const half8*)(Pt + ((size_t)(0 + lg) * 16 + lr) * 8);
      pa1[i] = *(const half8*)(Pt + ((size_t)(4 + lg) * 16 + lr) * 8);
    }
  }
  // v rows y0-1 .. y0+4 (coalesced: contiguous within each row)
  half8 sv[6];
  bool svok[6];
#pragma unroll
  for (int i = 0; i < 6; ++i) {
    int s = tid + i * 256;
    int ry = s / 224, rem = s - ry * 224;
    int gy = y0 - 1 + ry;
    svok[i] = (s < 1344) && (gy >= 0) && (gy < 56);
    if (svok[i])
      sv[i] = *(const half8*)(vp + (size_t)gy * 1792 + rem * 8);
  }
  // tables
  for (int s = tid; s < 32 * 64; s += 256) {
    int d = s >> 6, a = s & 63;
    avT[d][a] = (a < NA) ? (f16)agent_v[((size_t)bh * NA + a) * 32 + d] : (f16)0.f;
  }
  for (int s = tid; s < 32 * 9; s += 256) {
    int d = s / 9, t = s - d * 9;
    wconv[t][d] = dwc_w[(size_t)(h * 32 + d) * 9 + t];
  }
  if (tid < 32) bconv[tid] = dwc_b[h * 32 + tid];
  __syncthreads();
  // ---- phase A: MFMA P @ avT -> ctile ----
  half8 bf[2][2];
#pragma unroll
  for (int nt = 0; nt < 2; ++nt)
#pragma unroll
    for (int ks = 0; ks < 2; ++ks)
      bf[nt][ks] = *(const half8*)(&avT[0][0] + (size_t)(nt * 16 + lr) * 72 + ks * 32 + lg * 8);
#pragma unroll
  for (int i = 0; i < 4; ++i) {
    int lt = w * 4 + i;
    if (lt >= 14) continue;
    f32x4 acc0 = {}, acc1 = {};
    acc0 = mfma16(pa0[i], bf[0][0], acc0);
    acc0 = mfma16(pa1[i], bf[0][1], acc0);
    acc1 = mfma16(pa0[i], bf[1][0], acc1);
    acc1 = mfma16(pa1[i], bf[1][1], acc1);
    int ltrow = lt * 16 + lg * 4;
#pragma unroll
    for (int r = 0; r < 4; ++r) {
      ctile[ltrow + r][lr] = (f16)acc0[r];
      ctile[ltrow + r][16 + lr] = (f16)acc1[r];
    }
  }
  // ---- phase B: vtile writes ----
#pragma unroll
  for (int i = 0; i < 6; ++i) {
    if (svok[i]) {
      int s = tid + i * 256;
      int ry = s / 224, rem = s - ry * 224;
      int tok = rem >> 2, c = rem & 3;
      *(half8*)(&vtile[ry][tok][c * 8]) = sv[i];
    }
  }
  __syncthreads();
  // ---- phase C: epilogue per token ----
  if (tid >= 224) return;
  int g = chunk * 224 + tid;
  int ly = tid / 56, x = tid - ly * 56;
  int y = y0 + ly;
  float accd[32];
#pragma unroll
  for (int c = 0; c < 4; ++c) {
    half8 cv = *(const half8*)(&ctile[tid][c * 8]);
#pragma unroll
    for (int e = 0; e < 8; ++e) accd[c * 8 + e] = (float)cv[e] + bconv[c * 8 + e];
  }
#pragma unroll
  for (int ky = 0; ky < 3; ++ky) {
    int gy = y + ky - 1;
    if (gy < 0 || gy >= 56) continue;
    int ry = ly + ky;
#pragma unroll
    for (int kx = 0; kx < 3; ++kx) {
      int xx = x + kx - 1;
      if (xx < 0 || xx >= 56) continue;
      int t = ky * 3 + kx;
#pragma unroll
      for (int c = 0; c < 4; ++c) {
        half8 vv = *(const half8*)(&vtile[ry][xx][c * 8]);
#pragma unroll
        for (int e = 0; e < 8; ++e) accd[c * 8 + e] += wconv[t][c * 8 + e] * (float)vv[e];
      }
    }
  }
  f16* op = preH + ((size_t)h * NTOT + (size_t)b * NTOK + g) * 32;
#pragma unroll
  for (int c = 0; c < 4; ++c) {
    half8 o;
#pragma unroll
    for (int e = 0; e < 8; ++e) o[e] = (f16)accd[c * 8 + e];
    *(half8*)(op + c * 8) = o;
  }
}

extern "C" void kernel_launch(void* const* d_in, const int* in_sizes, int n_in,
                              void* d_out, int out_size, void* d_ws, size_t ws_size,
                              hipStream_t stream) {
  const float* x     = (const float*)d_in[0];
  const float* Wq    = (const float*)d_in[3];
  const float* Wkv   = (const float*)d_in[4];
  const float* Wproj = (const float*)d_in[5];
  const float* bproj = (const float*)d_in[6];
  const float* dwc_w = (const float*)d_in[7];
  const float* dwc_b = (const float*)d_in[8];
  const float* an_b  = (const float*)d_in[9];
  const float* na_b  = (const float*)d_in[10];
  const float* ah_b  = (const float*)d_in[11];
  const float* aw_b  = (const float*)d_in[12];
  const float* ha_b  = (const float*)d_in[13];
  const float* wa_b  = (const float*)d_in[14];

  char* ws = (char*)d_ws;
  size_t off = 0;
  auto alloc = [&](size_t bytes) {
    void* p = ws + off;
    off = (off + bytes + 255) & ~(size_t)255;
    return p;
  };
  f16* wqkv    = (f16*)alloc((size_t)768 * 256 * 2);
  f16* wproj   = (f16*)alloc((size_t)256 * 256 * 2);
  f16* qkvH    = (f16*)alloc((size_t)24 * NTOT * 32 * 2);
  float* posb  = (float*)alloc((size_t)8 * NAP * NTOK * 4);
  float* agb   = (float*)alloc((size_t)8 * NAP * NTOK * 4);
  f16* agent   = (f16*)alloc((size_t)128 * NAP * 32 * 2);
  float* tw    = (float*)alloc((size_t)128 * NTOK * 4);
  int* topidx  = (int*)alloc((size_t)128 * TTOP * 4);
  f16* vt      = (f16*)alloc((size_t)128 * 32 * NTOK * 2);
  float* agv   = (float*)alloc((size_t)128 * NA * 32 * 4);
  f16* preH    = (f16*)alloc((size_t)8 * NTOT * 32 * 2);
  f16* P       = (f16*)alloc((size_t)128 * PBH * 2);
  f16* xh      = P;        // P region dead until k_psm; xh dead after qkv GEMM

  k_prep_w<<<1024, 256, 0, stream>>>(Wq, Wkv, Wproj, wqkv, wproj);
  k_cvt_x<<<2048, 256, 0, stream>>>(x, xh, (long)NTOT * 256);
  k_bias<<<dim3(13, 8), 256, 0, stream>>>(an_b, na_b, ah_b, aw_b, ha_b, wa_b, posb, agb);
  k_gemm<false><<<2352, 256, 0, stream>>>(xh, wqkv, qkvH, nullptr, nullptr, 768);
  k_pool_tw<<<128, 256, 0, stream>>>(qkvH, agent, tw);
  k_topk<<<128, 1024, 0, stream>>>(tw, topidx);
  k_vt<<<dim3(49, 128), 256, 0, stream>>>(qkvH, vt);
  k_flash<<<128, 256, 0, stream>>>(qkvH, agent, vt, posb, agv);
  k_psm<<<dim3(13, 128), 256, 0, stream>>>(qkvH, agent, topidx, agb, P);
  k_out<<<dim3(14, 128), 256, 0, stream>>>(P, agv, qkvH, dwc_w, dwc_b, preH);
  k_gemm<true><<<784, 256, 0, stream>>>(preH, wproj, nullptr, (float*)d_out, bproj, 256);
}